// Round 2
// baseline (3451.105 us; speedup 1.0000x reference)
//
#include <hip/hip_runtime.h>
#include <hip/hip_bf16.h>

// Problem constants (MambaBlock): B=2, L=2048, d_model=1024, d_inner=2048,
// d_conv=4, dt_rank=64, d_state=16. All inputs/output float32 (per reference).

#define BATCH   2
#define SEQLEN  2048
#define DMODEL  1024
#define DINNER  2048
#define DCONV   4
#define DTRANK  64
#define DSTATE  16
#define BL      (BATCH * SEQLEN)         // 4096
#define NXZ     (2 * DINNER)             // 4096
#define XDBL_N  (DTRANK + 2 * DSTATE)    // 96

__device__ __forceinline__ float silu_f(float v) {
    return v / (1.f + __expf(-v));
}

// ---------------------------------------------------------------------------
// Tiled GEMM: C[M,N] = A[M,K] * B[K,N], fp32, fp32 accumulate.
// EPI: 0 = store fp32; 1 = softplus(acc + bias[col]) fp32
// BM=BN=64, BK=16, 256 threads, 4x4 micro-tile per thread.
// ---------------------------------------------------------------------------
template <int EPI>
__global__ __launch_bounds__(256) void gemm_tiled(
    const float* __restrict__ A, int lda,
    const float* __restrict__ B, int ldb,
    float* __restrict__ C, int ldc,
    int M, int N, int K,
    const float* __restrict__ bias)
{
    __shared__ float As[16][64 + 1];
    __shared__ float Bs[16][64 + 1];

    const int tid = threadIdx.x;
    const int row0 = blockIdx.y * 64;
    const int col0 = blockIdx.x * 64;
    const int tr = tid >> 4;        // 0..15
    const int tc = tid & 15;        // 0..15

    // loader mapping
    const int arow = tid >> 2;          // 0..63
    const int acol = (tid & 3) * 4;     // 0,4,8,12
    const int brow = tid >> 4;          // 0..15
    const int bcol = (tid & 15) * 4;    // 0..60

    float acc[4][4] = {};

    for (int k0 = 0; k0 < K; k0 += 16) {
#pragma unroll
        for (int j = 0; j < 4; ++j) {
            int gr = row0 + arow, gc = k0 + acol + j;
            float v = 0.f;
            if (gr < M && gc < K) v = A[(long)gr * lda + gc];
            As[acol + j][arow] = v;
        }
#pragma unroll
        for (int j = 0; j < 4; ++j) {
            int gr = k0 + brow, gc = col0 + bcol + j;
            float v = 0.f;
            if (gr < K && gc < N) v = B[(long)gr * ldb + gc];
            Bs[brow][bcol + j] = v;
        }
        __syncthreads();
#pragma unroll
        for (int kk = 0; kk < 16; ++kk) {
            float a[4], b[4];
#pragma unroll
            for (int i = 0; i < 4; ++i) a[i] = As[kk][tr * 4 + i];
#pragma unroll
            for (int j = 0; j < 4; ++j) b[j] = Bs[kk][tc * 4 + j];
#pragma unroll
            for (int i = 0; i < 4; ++i)
#pragma unroll
                for (int j = 0; j < 4; ++j)
                    acc[i][j] += a[i] * b[j];
        }
        __syncthreads();
    }

#pragma unroll
    for (int i = 0; i < 4; ++i) {
        int gr = row0 + tr * 4 + i;
        if (gr >= M) continue;
#pragma unroll
        for (int j = 0; j < 4; ++j) {
            int gc = col0 + tc * 4 + j;
            if (gc >= N) continue;
            float v = acc[i][j];
            if (EPI == 1) {
                v += bias[gc];
                v = (v > 20.f) ? v : log1pf(__expf(v));
            }
            C[(long)gr * ldc + gc] = v;
        }
    }
}

// ---------------------------------------------------------------------------
// Causal depthwise conv (d_conv=4) + SiLU.
// xb lives in xz[:, 0:DINNER] (fp32, stride NXZ). Output xc [BL, DINNER] fp32.
// ---------------------------------------------------------------------------
__global__ __launch_bounds__(256) void conv_silu_kernel(
    const float* __restrict__ xz,
    const float* __restrict__ cw,   // [DINNER, 4]
    const float* __restrict__ cb,   // [DINNER]
    float* __restrict__ xc)
{
    long i = (long)blockIdx.x * blockDim.x + threadIdx.x;
    if (i >= (long)BL * DINNER) return;
    long r = i / DINNER;
    int d = (int)(i % DINNER);
    int t = (int)(r % SEQLEN);

    float acc = cb[d];
#pragma unroll
    for (int k = 0; k < DCONV; ++k) {
        int tt = t - (DCONV - 1) + k;
        if (tt >= 0)
            acc += xz[(r - (DCONV - 1) + k) * NXZ + d] * cw[d * DCONV + k];
    }
    xc[i] = silu_f(acc);
}

// ---------------------------------------------------------------------------
// Selective scan: one thread per (b, d) channel, h[16] in registers.
// Writes y into xz[:, 0:DINNER] (xb region is dead after conv).
// ---------------------------------------------------------------------------
__global__ __launch_bounds__(256) void scan_kernel(
    const float* __restrict__ dt,     // [BL, DINNER]
    const float* __restrict__ xc,     // [BL, DINNER]
    const float* __restrict__ xdbl,   // [BL, 96]; B at 64..79, C at 80..95
    const float* __restrict__ A_log,  // [DINNER, 16]
    float* __restrict__ y_out)        // xz buffer, stride NXZ, col d
{
    int c = blockIdx.x * blockDim.x + threadIdx.x;
    if (c >= BATCH * DINNER) return;
    int b = c / DINNER;
    int d = c % DINNER;

    float Ad[DSTATE];
#pragma unroll
    for (int n = 0; n < DSTATE; ++n)
        Ad[n] = -__expf(A_log[d * DSTATE + n]);

    float h[DSTATE] = {};
    for (int t = 0; t < SEQLEN; ++t) {
        long r = (long)b * SEQLEN + t;
        float dtv = dt[r * DINNER + d];
        float xv = xc[r * DINNER + d];
        float xdt = xv * dtv;
        const float* bc = xdbl + r * XDBL_N + DTRANK;
        float y = 0.f;
#pragma unroll
        for (int n = 0; n < DSTATE; ++n) {
            float dA = __expf(Ad[n] * dtv);
            h[n] = h[n] * dA + xdt * bc[n];
            y += h[n] * bc[DSTATE + n];
        }
        y_out[r * NXZ + d] = y;
    }
}

// ---------------------------------------------------------------------------
// Gating: ygated = (y + xc * D) * silu(z). y in xz[:,0:DINNER], z in
// xz[:,DINNER:2*DINNER]. Output overwrites dt buffer [BL, DINNER].
// ---------------------------------------------------------------------------
__global__ __launch_bounds__(256) void gate_kernel(
    const float* __restrict__ xz,
    const float* __restrict__ xc,
    const float* __restrict__ Dp,
    float* __restrict__ outb)
{
    long i = (long)blockIdx.x * blockDim.x + threadIdx.x;
    if (i >= (long)BL * DINNER) return;
    long r = i / DINNER;
    int d = (int)(i % DINNER);
    float y = xz[r * NXZ + d];
    float z = xz[r * NXZ + DINNER + d];
    float yy = y + xc[i] * Dp[d];
    outb[i] = yy * silu_f(z);
}

// ---------------------------------------------------------------------------
extern "C" void kernel_launch(void* const* d_in, const int* in_sizes, int n_in,
                              void* d_out, int out_size, void* d_ws, size_t ws_size,
                              hipStream_t stream) {
    const float* x      = (const float*)d_in[0];  // [B,L,DMODEL]
    const float* W_in   = (const float*)d_in[1];  // [DMODEL, 2*DINNER]
    const float* conv_w = (const float*)d_in[2];  // [DINNER, 4]
    const float* conv_b = (const float*)d_in[3];  // [DINNER]
    const float* W_x    = (const float*)d_in[4];  // [DINNER, 96]
    const float* W_dt   = (const float*)d_in[5];  // [DTRANK, DINNER]
    const float* b_dt   = (const float*)d_in[6];  // [DINNER]
    const float* A_log  = (const float*)d_in[7];  // [DINNER, 16]
    const float* Dp     = (const float*)d_in[8];  // [DINNER]
    const float* W_out  = (const float*)d_in[9];  // [DINNER, DMODEL]
    float* out = (float*)d_out;                   // [B,L,DMODEL]

    float* ws = (float*)d_ws;
    float* xz   = ws;                                   // [BL, NXZ]
    float* xc   = xz + (long)BL * NXZ;                  // [BL, DINNER]
    float* xdbl = xc + (long)BL * DINNER;               // [BL, 96]
    float* dt   = xdbl + (long)BL * XDBL_N;             // [BL, DINNER]
    // total ~136 MB

    dim3 blk(256);

    // 1) xz = x @ W_in   [BL,DMODEL]@[DMODEL,NXZ]
    {
        dim3 grid(NXZ / 64, BL / 64);
        gemm_tiled<0><<<grid, blk, 0, stream>>>(
            x, DMODEL, W_in, NXZ, xz, NXZ, BL, NXZ, DMODEL, nullptr);
    }
    // 2) causal depthwise conv + silu -> xc
    {
        long total = (long)BL * DINNER;
        dim3 grid((unsigned)((total + 255) / 256));
        conv_silu_kernel<<<grid, blk, 0, stream>>>(xz, conv_w, conv_b, xc);
    }
    // 3) x_dbl = xc @ W_x   [BL,DINNER]@[DINNER,96]
    {
        dim3 grid((XDBL_N + 63) / 64, BL / 64);
        gemm_tiled<0><<<grid, blk, 0, stream>>>(
            xc, DINNER, W_x, XDBL_N, xdbl, XDBL_N, BL, XDBL_N, DINNER, nullptr);
    }
    // 4) dt = softplus(x_dbl[:, :64] @ W_dt + b_dt)   [BL,64]@[64,DINNER]
    {
        dim3 grid(DINNER / 64, BL / 64);
        gemm_tiled<1><<<grid, blk, 0, stream>>>(
            xdbl, XDBL_N, W_dt, DINNER, dt, DINNER, BL, DINNER, DTRANK, b_dt);
    }
    // 5) selective scan -> y into xz[:, 0:DINNER]
    {
        dim3 grid((BATCH * DINNER) / 256);
        scan_kernel<<<grid, blk, 0, stream>>>(dt, xc, xdbl, A_log, xz);
    }
    // 6) gating -> overwrite dt buffer with (y + xc*D) * silu(z)
    {
        long total = (long)BL * DINNER;
        dim3 grid((unsigned)((total + 255) / 256));
        gate_kernel<<<grid, blk, 0, stream>>>(xz, xc, Dp, dt);
    }
    // 7) out = ygated @ W_out   [BL,DINNER]@[DINNER,DMODEL]
    {
        dim3 grid(DMODEL / 64, BL / 64);
        gemm_tiled<0><<<grid, blk, 0, stream>>>(
            dt, DINNER, W_out, DMODEL, out, DMODEL, BL, DINNER, DINNER, nullptr);
    }

    (void)in_sizes; (void)n_in; (void)out_size; (void)ws_size;
}

// Round 3
// 1802.527 us; speedup vs baseline: 1.9146x; 1.9146x over previous
//
#include <hip/hip_runtime.h>
#include <hip/hip_bf16.h>

// Problem constants (MambaBlock): B=2, L=2048, d_model=1024, d_inner=2048,
// d_conv=4, dt_rank=64, d_state=16. All inputs/output float32 (per reference).

#define BATCH   2
#define SEQLEN  2048
#define DMODEL  1024
#define DINNER  2048
#define DCONV   4
#define DTRANK  64
#define DSTATE  16
#define BL      (BATCH * SEQLEN)         // 4096
#define NXZ     (2 * DINNER)             // 4096
#define XDBL_N  (DTRANK + 2 * DSTATE)    // 96
#define LCH     64                       // chunk length for parallel scan
#define NCHUNK  (SEQLEN / LCH)           // 32 chunks per sequence

__device__ __forceinline__ float silu_f(float v) {
    return v / (1.f + __expf(-v));
}

// ---------------------------------------------------------------------------
// Tiled GEMM: C[M,N] = A[M,K] * B[K,N], fp32, fp32 accumulate.
// EPI: 0 = store fp32; 1 = softplus(acc + bias[col]) fp32
// BM=BN=64, BK=16, 256 threads, 4x4 micro-tile per thread.
// ---------------------------------------------------------------------------
template <int EPI>
__global__ __launch_bounds__(256) void gemm_tiled(
    const float* __restrict__ A, int lda,
    const float* __restrict__ B, int ldb,
    float* __restrict__ C, int ldc,
    int M, int N, int K,
    const float* __restrict__ bias)
{
    __shared__ float As[16][64 + 1];
    __shared__ float Bs[16][64 + 1];

    const int tid = threadIdx.x;
    const int row0 = blockIdx.y * 64;
    const int col0 = blockIdx.x * 64;
    const int tr = tid >> 4;        // 0..15
    const int tc = tid & 15;        // 0..15

    const int arow = tid >> 2;          // 0..63
    const int acol = (tid & 3) * 4;     // 0,4,8,12
    const int brow = tid >> 4;          // 0..15
    const int bcol = (tid & 15) * 4;    // 0..60

    float acc[4][4] = {};

    for (int k0 = 0; k0 < K; k0 += 16) {
#pragma unroll
        for (int j = 0; j < 4; ++j) {
            int gr = row0 + arow, gc = k0 + acol + j;
            float v = 0.f;
            if (gr < M && gc < K) v = A[(long)gr * lda + gc];
            As[acol + j][arow] = v;
        }
#pragma unroll
        for (int j = 0; j < 4; ++j) {
            int gr = k0 + brow, gc = col0 + bcol + j;
            float v = 0.f;
            if (gr < K && gc < N) v = B[(long)gr * ldb + gc];
            Bs[brow][bcol + j] = v;
        }
        __syncthreads();
#pragma unroll
        for (int kk = 0; kk < 16; ++kk) {
            float a[4], b[4];
#pragma unroll
            for (int i = 0; i < 4; ++i) a[i] = As[kk][tr * 4 + i];
#pragma unroll
            for (int j = 0; j < 4; ++j) b[j] = Bs[kk][tc * 4 + j];
#pragma unroll
            for (int i = 0; i < 4; ++i)
#pragma unroll
                for (int j = 0; j < 4; ++j)
                    acc[i][j] += a[i] * b[j];
        }
        __syncthreads();
    }

#pragma unroll
    for (int i = 0; i < 4; ++i) {
        int gr = row0 + tr * 4 + i;
        if (gr >= M) continue;
#pragma unroll
        for (int j = 0; j < 4; ++j) {
            int gc = col0 + tc * 4 + j;
            if (gc >= N) continue;
            float v = acc[i][j];
            if (EPI == 1) {
                v += bias[gc];
                v = (v > 20.f) ? v : log1pf(__expf(v));
            }
            C[(long)gr * ldc + gc] = v;
        }
    }
}

// ---------------------------------------------------------------------------
// Causal depthwise conv (d_conv=4) + SiLU.
// xb lives in xz[:, 0:DINNER] (fp32, stride NXZ). Output xc [BL, DINNER] fp32.
// ---------------------------------------------------------------------------
__global__ __launch_bounds__(256) void conv_silu_kernel(
    const float* __restrict__ xz,
    const float* __restrict__ cw,   // [DINNER, 4]
    const float* __restrict__ cb,   // [DINNER]
    float* __restrict__ xc)
{
    long i = (long)blockIdx.x * blockDim.x + threadIdx.x;
    if (i >= (long)BL * DINNER) return;
    long r = i / DINNER;
    int d = (int)(i % DINNER);
    int t = (int)(r % SEQLEN);

    float acc = cb[d];
#pragma unroll
    for (int k = 0; k < DCONV; ++k) {
        int tt = t - (DCONV - 1) + k;
        if (tt >= 0)
            acc += xz[(r - (DCONV - 1) + k) * NXZ + d] * cw[d * DCONV + k];
    }
    xc[i] = silu_f(acc);
}

// ---------------------------------------------------------------------------
// Chunked parallel scan.
// Chunk summaries live in the DEAD xb half of xz (cols 0..2047):
//   hloc(b,c,n)  at row  (b*NCHUNK+c)*16 + n          (rows    0..1023)
//   P / hstart   at row  1024 + (b*NCHUNK+c)*16 + n   (rows 1024..2047)
// (xb half is dead after conv; z half cols 2048.. stays live for pass3.)
// ---------------------------------------------------------------------------

// Pass 1: per-(b,chunk,d) local scan with h0=0; emits hloc[16], P[16].
__global__ __launch_bounds__(256) void scan_pass1(
    const float* __restrict__ dt,     // [BL, DINNER]
    const float* __restrict__ xc,     // [BL, DINNER]
    const float* __restrict__ xdbl,   // [BL, 96]; B at 64..79
    const float* __restrict__ A_log,  // [DINNER, 16]
    float* __restrict__ sums)         // xz buffer (summary rows, stride NXZ)
{
    const int d  = blockIdx.x * 256 + threadIdx.x;
    const int bc = blockIdx.y;                 // (b*NCHUNK + c), wave-uniform
    const int b  = bc / NCHUNK, c = bc % NCHUNK;
    const long r0 = (long)b * SEQLEN + (long)c * LCH;

    float Ad[DSTATE];
    {
        const float4* al = (const float4*)(A_log + d * DSTATE);
#pragma unroll
        for (int q = 0; q < 4; ++q) {
            float4 v = al[q];
            Ad[q * 4 + 0] = -__expf(v.x); Ad[q * 4 + 1] = -__expf(v.y);
            Ad[q * 4 + 2] = -__expf(v.z); Ad[q * 4 + 3] = -__expf(v.w);
        }
    }

    float h[DSTATE] = {};
    float Pp[DSTATE];
#pragma unroll
    for (int n = 0; n < DSTATE; ++n) Pp[n] = 1.f;

    for (int t = 0; t < LCH; ++t) {
        long r = r0 + t;
        float dtv = dt[r * DINNER + d];
        float xv  = xc[r * DINNER + d];
        float xdt = xv * dtv;
        const float4* bv = (const float4*)(xdbl + r * XDBL_N + DTRANK);
        float4 B0 = bv[0], B1 = bv[1], B2 = bv[2], B3 = bv[3];
        const float Bn[DSTATE] = {B0.x,B0.y,B0.z,B0.w, B1.x,B1.y,B1.z,B1.w,
                                  B2.x,B2.y,B2.z,B2.w, B3.x,B3.y,B3.z,B3.w};
#pragma unroll
        for (int n = 0; n < DSTATE; ++n) {
            float dA = __expf(Ad[n] * dtv);
            h[n] = h[n] * dA + xdt * Bn[n];
            Pp[n] *= dA;
        }
    }

    const long rowbase = (long)bc * DSTATE;
#pragma unroll
    for (int n = 0; n < DSTATE; ++n) {
        sums[(rowbase + n) * NXZ + d] = h[n];
        sums[(1024 + rowbase + n) * NXZ + d] = Pp[n];
    }
}

// Pass 2: sequential combine over NCHUNK summaries; rewrites P rows as hstart.
__global__ __launch_bounds__(256) void scan_combine(float* __restrict__ sums)
{
    int u = blockIdx.x * 256 + threadIdx.x;   // B*DSTATE*DINNER = 65536
    int d = u & (DINNER - 1);
    int n = (u >> 11) & (DSTATE - 1);
    int b = u >> 15;
    float hg = 0.f;
    for (int c = 0; c < NCHUNK; ++c) {
        long row = (long)(b * NCHUNK + c) * DSTATE + n;
        float p  = sums[(1024 + row) * NXZ + d];
        float hl = sums[row * NXZ + d];
        sums[(1024 + row) * NXZ + d] = hg;    // hstart for this chunk
        hg = p * hg + hl;
    }
}

// Pass 3: replay chunk from hstart, compute y, fuse gate:
//   dtg[r,d] <- (y + xc*D) * silu(z)   (in-place over the dt buffer)
__global__ __launch_bounds__(256) void scan_pass3(
    float* dtg,                       // [BL, DINNER]: dt in, gated out
    const float* __restrict__ xc,     // [BL, DINNER]
    const float* __restrict__ xdbl,   // [BL, 96]; B 64..79, C 80..95
    const float* __restrict__ A_log,  // [DINNER, 16]
    const float* __restrict__ xz,     // z half + hstart summary rows
    const float* __restrict__ Dp)     // [DINNER]
{
    const int d  = blockIdx.x * 256 + threadIdx.x;
    const int bc = blockIdx.y;
    const int b  = bc / NCHUNK, c = bc % NCHUNK;
    const long r0 = (long)b * SEQLEN + (long)c * LCH;

    float Ad[DSTATE];
    {
        const float4* al = (const float4*)(A_log + d * DSTATE);
#pragma unroll
        for (int q = 0; q < 4; ++q) {
            float4 v = al[q];
            Ad[q * 4 + 0] = -__expf(v.x); Ad[q * 4 + 1] = -__expf(v.y);
            Ad[q * 4 + 2] = -__expf(v.z); Ad[q * 4 + 3] = -__expf(v.w);
        }
    }

    float h[DSTATE];
    const long rowbase = (long)bc * DSTATE;
#pragma unroll
    for (int n = 0; n < DSTATE; ++n)
        h[n] = xz[(1024 + rowbase + n) * NXZ + d];

    const float Dv = Dp[d];

    for (int t = 0; t < LCH; ++t) {
        long r = r0 + t;
        float dtv = dtg[r * DINNER + d];
        float xv  = xc[r * DINNER + d];
        float xdt = xv * dtv;
        const float4* bv = (const float4*)(xdbl + r * XDBL_N + DTRANK);
        float4 B0 = bv[0], B1 = bv[1], B2 = bv[2], B3 = bv[3];
        float4 C0 = bv[4], C1 = bv[5], C2 = bv[6], C3 = bv[7];
        const float Bn[DSTATE] = {B0.x,B0.y,B0.z,B0.w, B1.x,B1.y,B1.z,B1.w,
                                  B2.x,B2.y,B2.z,B2.w, B3.x,B3.y,B3.z,B3.w};
        const float Cn[DSTATE] = {C0.x,C0.y,C0.z,C0.w, C1.x,C1.y,C1.z,C1.w,
                                  C2.x,C2.y,C2.z,C2.w, C3.x,C3.y,C3.z,C3.w};
        float y = 0.f;
#pragma unroll
        for (int n = 0; n < DSTATE; ++n) {
            float dA = __expf(Ad[n] * dtv);
            h[n] = h[n] * dA + xdt * Bn[n];
            y += h[n] * Cn[n];
        }
        float z = xz[r * NXZ + DINNER + d];
        float yy = y + xv * Dv;
        dtg[r * DINNER + d] = yy * silu_f(z);
    }
}

// ---------------------------------------------------------------------------
extern "C" void kernel_launch(void* const* d_in, const int* in_sizes, int n_in,
                              void* d_out, int out_size, void* d_ws, size_t ws_size,
                              hipStream_t stream) {
    const float* x      = (const float*)d_in[0];  // [B,L,DMODEL]
    const float* W_in   = (const float*)d_in[1];  // [DMODEL, 2*DINNER]
    const float* conv_w = (const float*)d_in[2];  // [DINNER, 4]
    const float* conv_b = (const float*)d_in[3];  // [DINNER]
    const float* W_x    = (const float*)d_in[4];  // [DINNER, 96]
    const float* W_dt   = (const float*)d_in[5];  // [DTRANK, DINNER]
    const float* b_dt   = (const float*)d_in[6];  // [DINNER]
    const float* A_log  = (const float*)d_in[7];  // [DINNER, 16]
    const float* Dp     = (const float*)d_in[8];  // [DINNER]
    const float* W_out  = (const float*)d_in[9];  // [DINNER, DMODEL]
    float* out = (float*)d_out;                   // [B,L,DMODEL]

    float* ws = (float*)d_ws;
    float* xz   = ws;                                   // [BL, NXZ]
    float* xc   = xz + (long)BL * NXZ;                  // [BL, DINNER]
    float* xdbl = xc + (long)BL * DINNER;               // [BL, 96]
    float* dt   = xdbl + (long)BL * XDBL_N;             // [BL, DINNER]
    // total ~136 MB (chunk summaries reuse dead xb half of xz)

    dim3 blk(256);

    // 1) xz = x @ W_in   [BL,DMODEL]@[DMODEL,NXZ]
    {
        dim3 grid(NXZ / 64, BL / 64);
        gemm_tiled<0><<<grid, blk, 0, stream>>>(
            x, DMODEL, W_in, NXZ, xz, NXZ, BL, NXZ, DMODEL, nullptr);
    }
    // 2) causal depthwise conv + silu -> xc
    {
        long total = (long)BL * DINNER;
        dim3 grid((unsigned)((total + 255) / 256));
        conv_silu_kernel<<<grid, blk, 0, stream>>>(xz, conv_w, conv_b, xc);
    }
    // 3) x_dbl = xc @ W_x   [BL,DINNER]@[DINNER,96]
    {
        dim3 grid((XDBL_N + 63) / 64, BL / 64);
        gemm_tiled<0><<<grid, blk, 0, stream>>>(
            xc, DINNER, W_x, XDBL_N, xdbl, XDBL_N, BL, XDBL_N, DINNER, nullptr);
    }
    // 4) dt = softplus(x_dbl[:, :64] @ W_dt + b_dt)   [BL,64]@[64,DINNER]
    {
        dim3 grid(DINNER / 64, BL / 64);
        gemm_tiled<1><<<grid, blk, 0, stream>>>(
            xdbl, XDBL_N, W_dt, DINNER, dt, DINNER, BL, DINNER, DTRANK, b_dt);
    }
    // 5) chunked scan: local scans -> combine -> replay + fused gate
    {
        dim3 grid1(DINNER / 256, BATCH * NCHUNK);
        scan_pass1<<<grid1, blk, 0, stream>>>(dt, xc, xdbl, A_log, xz);

        dim3 grid2((BATCH * DSTATE * DINNER) / 256);
        scan_combine<<<grid2, blk, 0, stream>>>(xz);

        scan_pass3<<<grid1, blk, 0, stream>>>(dt, xc, xdbl, A_log, xz, Dp);
    }
    // 7) out = gated @ W_out   [BL,DINNER]@[DINNER,DMODEL]
    {
        dim3 grid(DMODEL / 64, BL / 64);
        gemm_tiled<0><<<grid, blk, 0, stream>>>(
            dt, DINNER, W_out, DMODEL, out, DMODEL, BL, DINNER, DINNER, nullptr);
    }

    (void)in_sizes; (void)n_in; (void)out_size; (void)ws_size;
}

// Round 4
// 655.403 us; speedup vs baseline: 5.2656x; 2.7503x over previous
//
#include <hip/hip_runtime.h>
#include <hip/hip_bf16.h>

// Problem constants (MambaBlock): B=2, L=2048, d_model=1024, d_inner=2048,
// d_conv=4, dt_rank=64, d_state=16. All inputs/output float32 (per reference).

#define BATCH   2
#define SEQLEN  2048
#define DMODEL  1024
#define DINNER  2048
#define DCONV   4
#define DTRANK  64
#define DSTATE  16
#define BL      (BATCH * SEQLEN)         // 4096
#define NXZ     (2 * DINNER)             // 4096
#define XDBL_N  (DTRANK + 2 * DSTATE)    // 96
#define LCH     64                       // chunk length for parallel scan
#define NCHUNK  (SEQLEN / LCH)           // 32 chunks per sequence

typedef __bf16 bf16x8 __attribute__((ext_vector_type(8)));
typedef __bf16 bf16x4 __attribute__((ext_vector_type(4)));
typedef float  floatx4 __attribute__((ext_vector_type(4)));

__device__ __forceinline__ float silu_f(float v) {
    return v / (1.f + __expf(-v));
}

__device__ __forceinline__ void gload_lds16(const __bf16* g, __bf16* l) {
    __builtin_amdgcn_global_load_lds(
        (const __attribute__((address_space(1))) void*)g,
        (__attribute__((address_space(3))) void*)l, 16, 0, 0);
}

// ---------------------------------------------------------------------------
// MFMA bf16 GEMM (m97 structure): C[M,N] = A[M,K] * B[K,N], fp32 out.
// A [M,K] bf16 row-major; BT [N,K] bf16 row-major (B transposed).
// 128x128 tile, BK=32, 256 threads = 4 waves (2x2 of 64x64), 4x4 MFMA tiles.
// M,N multiples of 128; K multiple of 32.
// ---------------------------------------------------------------------------
__global__ __launch_bounds__(256) void gemm_bt_mfma(
    const __bf16* __restrict__ A,
    const __bf16* __restrict__ BT,
    float* __restrict__ C,
    int M, int N, int K)
{
    __shared__ __bf16 Asm[128 * 32];
    __shared__ __bf16 Bsm[128 * 32];

    const int tid  = threadIdx.x;
    const int w    = tid >> 6;
    const int lane = tid & 63;
    const int lrow = lane & 15;
    const int quad = lane >> 4;
    const int row0 = blockIdx.y * 128;
    const int col0 = blockIdx.x * 128;
    const int wr   = (w >> 1) * 64;       // wave's row offset in tile
    const int wc   = (w & 1) * 64;        // wave's col offset in tile

    // staging: thread i covers tile row i/4 (or +64), k-bytes (i%4)*16
    const int ldr = tid >> 2;
    const int ldk = (tid & 3) * 8;
    const __bf16* gA = A  + (size_t)(row0 + ldr) * K + ldk;
    const __bf16* gB = BT + (size_t)(col0 + ldr) * K + ldk;
    const size_t half = (size_t)64 * K;
    __bf16* lA0 = Asm + w * 512;          // wave-uniform LDS bases
    __bf16* lA1 = Asm + 2048 + w * 512;
    __bf16* lB0 = Bsm + w * 512;
    __bf16* lB1 = Bsm + 2048 + w * 512;

    floatx4 acc[4][4];
#pragma unroll
    for (int i = 0; i < 4; ++i)
#pragma unroll
        for (int j = 0; j < 4; ++j)
            acc[i][j] = (floatx4){0.f, 0.f, 0.f, 0.f};

    for (int k0 = 0; k0 < K; k0 += 32) {
        gload_lds16(gA, lA0);
        gload_lds16(gA + half, lA1);
        gload_lds16(gB, lB0);
        gload_lds16(gB + half, lB1);
        gA += 32; gB += 32;
        __syncthreads();

        bf16x8 af[4], bf[4];
#pragma unroll
        for (int t = 0; t < 4; ++t)
            af[t] = *(const bf16x8*)(Asm + (wr + t * 16 + lrow) * 32 + quad * 8);
#pragma unroll
        for (int t = 0; t < 4; ++t)
            bf[t] = *(const bf16x8*)(Bsm + (wc + t * 16 + lrow) * 32 + quad * 8);

#pragma unroll
        for (int ti = 0; ti < 4; ++ti)
#pragma unroll
            for (int tj = 0; tj < 4; ++tj)
                acc[ti][tj] = __builtin_amdgcn_mfma_f32_16x16x32_bf16(
                    af[ti], bf[tj], acc[ti][tj], 0, 0, 0);
        __syncthreads();
    }

    // C/D layout: col = lane&15, row = quad*4 + reg
#pragma unroll
    for (int ti = 0; ti < 4; ++ti) {
#pragma unroll
        for (int tj = 0; tj < 4; ++tj) {
            int col = col0 + wc + tj * 16 + lrow;
#pragma unroll
            for (int r = 0; r < 4; ++r) {
                int row = row0 + wr + ti * 16 + quad * 4 + r;
                C[(size_t)row * N + col] = acc[ti][tj][r];
            }
        }
    }
}

// ---------------------------------------------------------------------------
// fp32 -> bf16 cast (vectorized 4/thread); n divisible by 1024.
// ---------------------------------------------------------------------------
__global__ __launch_bounds__(256) void cast_bf16_kernel(
    const float* __restrict__ src, __bf16* __restrict__ dst, long n)
{
    long i = ((long)blockIdx.x * 256 + threadIdx.x) * 4;
    if (i >= n) return;
    float4 v = *(const float4*)(src + i);
    bf16x4 o = {(__bf16)v.x, (__bf16)v.y, (__bf16)v.z, (__bf16)v.w};
    *(bf16x4*)(dst + i) = o;
}

// ---------------------------------------------------------------------------
// Transpose-cast: src fp32 [R,Cc] -> dst bf16 [Cc,R]. R,Cc multiples of 32.
// ---------------------------------------------------------------------------
__global__ __launch_bounds__(256) void transpose_cast(
    const float* __restrict__ src, __bf16* __restrict__ dst, int R, int Cc)
{
    __shared__ float tile[32][33];
    int c0 = blockIdx.x * 32, r0 = blockIdx.y * 32;
    int tx = threadIdx.x, ty = threadIdx.y;   // 32 x 8
#pragma unroll
    for (int i = 0; i < 32; i += 8)
        tile[ty + i][tx] = src[(size_t)(r0 + ty + i) * Cc + c0 + tx];
    __syncthreads();
#pragma unroll
    for (int i = 0; i < 32; i += 8)
        dst[(size_t)(c0 + ty + i) * R + r0 + tx] = (__bf16)tile[tx][ty + i];
}

// ---------------------------------------------------------------------------
// Tiled vector GEMM (for the two small GEMMs): C = A*B fp32.
// EPI: 0 = store fp32; 1 = softplus(acc + bias[col])
// ---------------------------------------------------------------------------
template <int EPI>
__global__ __launch_bounds__(256) void gemm_tiled(
    const float* __restrict__ A, int lda,
    const float* __restrict__ B, int ldb,
    float* __restrict__ C, int ldc,
    int M, int N, int K,
    const float* __restrict__ bias)
{
    __shared__ float As[16][64 + 1];
    __shared__ float Bs[16][64 + 1];

    const int tid = threadIdx.x;
    const int row0 = blockIdx.y * 64;
    const int col0 = blockIdx.x * 64;
    const int tr = tid >> 4;
    const int tc = tid & 15;

    const int arow = tid >> 2;
    const int acol = (tid & 3) * 4;
    const int brow = tid >> 4;
    const int bcol = (tid & 15) * 4;

    float acc[4][4] = {};

    for (int k0 = 0; k0 < K; k0 += 16) {
#pragma unroll
        for (int j = 0; j < 4; ++j) {
            int gr = row0 + arow, gc = k0 + acol + j;
            float v = 0.f;
            if (gr < M && gc < K) v = A[(long)gr * lda + gc];
            As[acol + j][arow] = v;
        }
#pragma unroll
        for (int j = 0; j < 4; ++j) {
            int gr = k0 + brow, gc = col0 + bcol + j;
            float v = 0.f;
            if (gr < K && gc < N) v = B[(long)gr * ldb + gc];
            Bs[brow][bcol + j] = v;
        }
        __syncthreads();
#pragma unroll
        for (int kk = 0; kk < 16; ++kk) {
            float a[4], b[4];
#pragma unroll
            for (int i = 0; i < 4; ++i) a[i] = As[kk][tr * 4 + i];
#pragma unroll
            for (int j = 0; j < 4; ++j) b[j] = Bs[kk][tc * 4 + j];
#pragma unroll
            for (int i = 0; i < 4; ++i)
#pragma unroll
                for (int j = 0; j < 4; ++j)
                    acc[i][j] += a[i] * b[j];
        }
        __syncthreads();
    }

#pragma unroll
    for (int i = 0; i < 4; ++i) {
        int gr = row0 + tr * 4 + i;
        if (gr >= M) continue;
#pragma unroll
        for (int j = 0; j < 4; ++j) {
            int gc = col0 + tc * 4 + j;
            if (gc >= N) continue;
            float v = acc[i][j];
            if (EPI == 1) {
                v += bias[gc];
                v = (v > 20.f) ? v : log1pf(__expf(v));
            }
            C[(long)gr * ldc + gc] = v;
        }
    }
}

// ---------------------------------------------------------------------------
// Causal depthwise conv (d_conv=4) + SiLU.
// ---------------------------------------------------------------------------
__global__ __launch_bounds__(256) void conv_silu_kernel(
    const float* __restrict__ xz,
    const float* __restrict__ cw,
    const float* __restrict__ cb,
    float* __restrict__ xc)
{
    long i = (long)blockIdx.x * blockDim.x + threadIdx.x;
    if (i >= (long)BL * DINNER) return;
    long r = i / DINNER;
    int d = (int)(i % DINNER);
    int t = (int)(r % SEQLEN);

    float acc = cb[d];
#pragma unroll
    for (int k = 0; k < DCONV; ++k) {
        int tt = t - (DCONV - 1) + k;
        if (tt >= 0)
            acc += xz[(r - (DCONV - 1) + k) * NXZ + d] * cw[d * DCONV + k];
    }
    xc[i] = silu_f(acc);
}

// ---------------------------------------------------------------------------
// Chunked parallel scan. Summaries live in dead xb half of xz:
//   hloc(b,c,n) at row (b*NCHUNK+c)*16+n;  P/hstart at row 1024 + same.
// ---------------------------------------------------------------------------
__global__ __launch_bounds__(256) void scan_pass1(
    const float* __restrict__ dt,
    const float* __restrict__ xc,
    const float* __restrict__ xdbl,
    const float* __restrict__ A_log,
    float* __restrict__ sums)
{
    const int d  = blockIdx.x * 256 + threadIdx.x;
    const int bc = blockIdx.y;
    const int b  = bc / NCHUNK, c = bc % NCHUNK;
    const long r0 = (long)b * SEQLEN + (long)c * LCH;

    float Ad[DSTATE];
    {
        const float4* al = (const float4*)(A_log + d * DSTATE);
#pragma unroll
        for (int q = 0; q < 4; ++q) {
            float4 v = al[q];
            Ad[q * 4 + 0] = -__expf(v.x); Ad[q * 4 + 1] = -__expf(v.y);
            Ad[q * 4 + 2] = -__expf(v.z); Ad[q * 4 + 3] = -__expf(v.w);
        }
    }

    float h[DSTATE] = {};
    float Pp[DSTATE];
#pragma unroll
    for (int n = 0; n < DSTATE; ++n) Pp[n] = 1.f;

    for (int t = 0; t < LCH; ++t) {
        long r = r0 + t;
        float dtv = dt[r * DINNER + d];
        float xv  = xc[r * DINNER + d];
        float xdt = xv * dtv;
        const float4* bv = (const float4*)(xdbl + r * XDBL_N + DTRANK);
        float4 B0 = bv[0], B1 = bv[1], B2 = bv[2], B3 = bv[3];
        const float Bn[DSTATE] = {B0.x,B0.y,B0.z,B0.w, B1.x,B1.y,B1.z,B1.w,
                                  B2.x,B2.y,B2.z,B2.w, B3.x,B3.y,B3.z,B3.w};
#pragma unroll
        for (int n = 0; n < DSTATE; ++n) {
            float dA = __expf(Ad[n] * dtv);
            h[n] = h[n] * dA + xdt * Bn[n];
            Pp[n] *= dA;
        }
    }

    const long rowbase = (long)bc * DSTATE;
#pragma unroll
    for (int n = 0; n < DSTATE; ++n) {
        sums[(rowbase + n) * NXZ + d] = h[n];
        sums[(1024 + rowbase + n) * NXZ + d] = Pp[n];
    }
}

__global__ __launch_bounds__(256) void scan_combine(float* __restrict__ sums)
{
    int u = blockIdx.x * 256 + threadIdx.x;
    int d = u & (DINNER - 1);
    int n = (u >> 11) & (DSTATE - 1);
    int b = u >> 15;
    float hg = 0.f;
    for (int c = 0; c < NCHUNK; ++c) {
        long row = (long)(b * NCHUNK + c) * DSTATE + n;
        float p  = sums[(1024 + row) * NXZ + d];
        float hl = sums[row * NXZ + d];
        sums[(1024 + row) * NXZ + d] = hg;
        hg = p * hg + hl;
    }
}

// Pass 3: replay from hstart, fused gate, emit bf16 gated activation.
__global__ __launch_bounds__(256) void scan_pass3(
    const float* __restrict__ dt,
    const float* __restrict__ xc,
    const float* __restrict__ xdbl,
    const float* __restrict__ A_log,
    const float* __restrict__ xz,     // z half + hstart rows
    const float* __restrict__ Dp,
    __bf16* __restrict__ gated)       // [BL, DINNER] bf16
{
    const int d  = blockIdx.x * 256 + threadIdx.x;
    const int bc = blockIdx.y;
    const int b  = bc / NCHUNK, c = bc % NCHUNK;
    const long r0 = (long)b * SEQLEN + (long)c * LCH;

    float Ad[DSTATE];
    {
        const float4* al = (const float4*)(A_log + d * DSTATE);
#pragma unroll
        for (int q = 0; q < 4; ++q) {
            float4 v = al[q];
            Ad[q * 4 + 0] = -__expf(v.x); Ad[q * 4 + 1] = -__expf(v.y);
            Ad[q * 4 + 2] = -__expf(v.z); Ad[q * 4 + 3] = -__expf(v.w);
        }
    }

    float h[DSTATE];
    const long rowbase = (long)bc * DSTATE;
#pragma unroll
    for (int n = 0; n < DSTATE; ++n)
        h[n] = xz[(1024 + rowbase + n) * NXZ + d];

    const float Dv = Dp[d];

    for (int t = 0; t < LCH; ++t) {
        long r = r0 + t;
        float dtv = dt[r * DINNER + d];
        float xv  = xc[r * DINNER + d];
        float xdt = xv * dtv;
        const float4* bv = (const float4*)(xdbl + r * XDBL_N + DTRANK);
        float4 B0 = bv[0], B1 = bv[1], B2 = bv[2], B3 = bv[3];
        float4 C0 = bv[4], C1 = bv[5], C2 = bv[6], C3 = bv[7];
        const float Bn[DSTATE] = {B0.x,B0.y,B0.z,B0.w, B1.x,B1.y,B1.z,B1.w,
                                  B2.x,B2.y,B2.z,B2.w, B3.x,B3.y,B3.z,B3.w};
        const float Cn[DSTATE] = {C0.x,C0.y,C0.z,C0.w, C1.x,C1.y,C1.z,C1.w,
                                  C2.x,C2.y,C2.z,C2.w, C3.x,C3.y,C3.z,C3.w};
        float y = 0.f;
#pragma unroll
        for (int n = 0; n < DSTATE; ++n) {
            float dA = __expf(Ad[n] * dtv);
            h[n] = h[n] * dA + xdt * Bn[n];
            y += h[n] * Cn[n];
        }
        float z = xz[r * NXZ + DINNER + d];
        float yy = y + xv * Dv;
        gated[r * DINNER + d] = (__bf16)(yy * silu_f(z));
    }
}

// ---------------------------------------------------------------------------
extern "C" void kernel_launch(void* const* d_in, const int* in_sizes, int n_in,
                              void* d_out, int out_size, void* d_ws, size_t ws_size,
                              hipStream_t stream) {
    const float* x      = (const float*)d_in[0];  // [B,L,DMODEL]
    const float* W_in   = (const float*)d_in[1];  // [DMODEL, NXZ]
    const float* conv_w = (const float*)d_in[2];  // [DINNER, 4]
    const float* conv_b = (const float*)d_in[3];  // [DINNER]
    const float* W_x    = (const float*)d_in[4];  // [DINNER, 96]
    const float* W_dt   = (const float*)d_in[5];  // [DTRANK, DINNER]
    const float* b_dt   = (const float*)d_in[6];  // [DINNER]
    const float* A_log  = (const float*)d_in[7];  // [DINNER, 16]
    const float* Dp     = (const float*)d_in[8];  // [DINNER]
    const float* W_out  = (const float*)d_in[9];  // [DINNER, DMODEL]
    float* out = (float*)d_out;                   // [B,L,DMODEL]

    float* ws = (float*)d_ws;
    float* xz   = ws;                                   // 16.78M floats
    float* xc   = xz + (long)BL * NXZ;                  //  8.39M
    float* xdbl = xc + (long)BL * DINNER;               //  0.39M
    float* dt   = xdbl + (long)BL * XDBL_N;             //  8.39M
    __bf16* gated16 = (__bf16*)(dt + (long)BL * DINNER);        // 8.39M bf16
    __bf16* WoT16   = (__bf16*)((float*)gated16 + (long)BL * DINNER / 2); // 2.10M bf16
    // xb16 / W_inT16 alias the xc region (dead until conv, which runs after GEMM1)
    __bf16* xb16  = (__bf16*)xc;                        // 4.19M bf16
    __bf16* WiT16 = (__bf16*)(xc + (long)BL * DMODEL / 2); // 4.19M bf16
    // total ws ~157 MB

    dim3 blk(256);

    // 0) casts: x -> bf16; W_in -> bf16^T; W_out -> bf16^T
    cast_bf16_kernel<<<dim3((BL * DMODEL / 4) / 256), blk, 0, stream>>>(
        x, xb16, (long)BL * DMODEL);
    transpose_cast<<<dim3(NXZ / 32, DMODEL / 32), dim3(32, 8), 0, stream>>>(
        W_in, WiT16, DMODEL, NXZ);
    transpose_cast<<<dim3(DMODEL / 32, DINNER / 32), dim3(32, 8), 0, stream>>>(
        W_out, WoT16, DINNER, DMODEL);

    // 1) xz = x @ W_in   (MFMA bf16)
    gemm_bt_mfma<<<dim3(NXZ / 128, BL / 128), blk, 0, stream>>>(
        xb16, WiT16, xz, BL, NXZ, DMODEL);

    // 2) causal depthwise conv + silu -> xc (overwrites xb16/WiT16 — dead now)
    {
        long total = (long)BL * DINNER;
        conv_silu_kernel<<<dim3((unsigned)((total + 255) / 256)), blk, 0, stream>>>(
            xz, conv_w, conv_b, xc);
    }
    // 3) x_dbl = xc @ W_x
    gemm_tiled<0><<<dim3((XDBL_N + 63) / 64, BL / 64), blk, 0, stream>>>(
        xc, DINNER, W_x, XDBL_N, xdbl, XDBL_N, BL, XDBL_N, DINNER, nullptr);

    // 4) dt = softplus(x_dbl[:, :64] @ W_dt + b_dt)
    gemm_tiled<1><<<dim3(DINNER / 64, BL / 64), blk, 0, stream>>>(
        xdbl, XDBL_N, W_dt, DINNER, dt, DINNER, BL, DINNER, DTRANK, b_dt);

    // 5) chunked scan: pass1 -> combine -> pass3 (+fused gate, bf16 out)
    {
        dim3 grid1(DINNER / 256, BATCH * NCHUNK);
        scan_pass1<<<grid1, blk, 0, stream>>>(dt, xc, xdbl, A_log, xz);
        scan_combine<<<dim3((BATCH * DSTATE * DINNER) / 256), blk, 0, stream>>>(xz);
        scan_pass3<<<grid1, blk, 0, stream>>>(dt, xc, xdbl, A_log, xz, Dp, gated16);
    }
    // 7) out = gated @ W_out   (MFMA bf16)
    gemm_bt_mfma<<<dim3(DMODEL / 128, BL / 128), blk, 0, stream>>>(
        gated16, WoT16, out, BL, DMODEL, DINNER);

    (void)in_sizes; (void)n_in; (void)out_size; (void)ws_size;
}

// Round 5
// 430.147 us; speedup vs baseline: 8.0231x; 1.5237x over previous
//
#include <hip/hip_runtime.h>
#include <hip/hip_bf16.h>

// Problem constants (MambaBlock): B=2, L=2048, d_model=1024, d_inner=2048,
// d_conv=4, dt_rank=64, d_state=16. All inputs/output float32 (per reference).

#define BATCH   2
#define SEQLEN  2048
#define DMODEL  1024
#define DINNER  2048
#define DCONV   4
#define DTRANK  64
#define DSTATE  16
#define BL      (BATCH * SEQLEN)         // 4096
#define NXZ     (2 * DINNER)             // 4096
#define XDBL_N  (DTRANK + 2 * DSTATE)    // 96
#define LCH     64                       // chunk length for parallel scan
#define NCHUNK  (SEQLEN / LCH)           // 32 chunks per sequence
#define KSPLIT  16                       // split-K for the x_dbl GEMM
#define KC      (DINNER / KSPLIT)        // 128

typedef __bf16 bf16x8 __attribute__((ext_vector_type(8)));
typedef __bf16 bf16x4 __attribute__((ext_vector_type(4)));
typedef float  floatx4 __attribute__((ext_vector_type(4)));

__device__ __forceinline__ float silu_f(float v) {
    return v / (1.f + __expf(-v));
}

__device__ __forceinline__ void gload_lds16(const __bf16* g, __bf16* l) {
    __builtin_amdgcn_global_load_lds(
        (const __attribute__((address_space(1))) void*)g,
        (__attribute__((address_space(3))) void*)l, 16, 0, 0);
}

// Partials for split-K x_dbl live in the dead xb half of xz:
// flat pidx -> xz[(pidx>>11) * NXZ + (pidx & 2047)], pidx < 16*4096*96 = 6.3M
// (rows 0..3071, cols 0..2047; z half cols 2048.. stays live).
__device__ __forceinline__ long part_off(long pidx) {
    return (pidx >> 11) * NXZ + (pidx & 2047);
}

// ---------------------------------------------------------------------------
// MFMA bf16 GEMM (m97 structure): C[M,N] = A[M,K] * B[K,N], fp32 out.
// ---------------------------------------------------------------------------
__global__ __launch_bounds__(256) void gemm_bt_mfma(
    const __bf16* __restrict__ A,
    const __bf16* __restrict__ BT,
    float* __restrict__ C,
    int M, int N, int K)
{
    __shared__ __bf16 Asm[128 * 32];
    __shared__ __bf16 Bsm[128 * 32];

    const int tid  = threadIdx.x;
    const int w    = tid >> 6;
    const int lane = tid & 63;
    const int lrow = lane & 15;
    const int quad = lane >> 4;
    const int row0 = blockIdx.y * 128;
    const int col0 = blockIdx.x * 128;
    const int wr   = (w >> 1) * 64;
    const int wc   = (w & 1) * 64;

    const int ldr = tid >> 2;
    const int ldk = (tid & 3) * 8;
    const __bf16* gA = A  + (size_t)(row0 + ldr) * K + ldk;
    const __bf16* gB = BT + (size_t)(col0 + ldr) * K + ldk;
    const size_t half = (size_t)64 * K;
    __bf16* lA0 = Asm + w * 512;
    __bf16* lA1 = Asm + 2048 + w * 512;
    __bf16* lB0 = Bsm + w * 512;
    __bf16* lB1 = Bsm + 2048 + w * 512;

    floatx4 acc[4][4];
#pragma unroll
    for (int i = 0; i < 4; ++i)
#pragma unroll
        for (int j = 0; j < 4; ++j)
            acc[i][j] = (floatx4){0.f, 0.f, 0.f, 0.f};

    for (int k0 = 0; k0 < K; k0 += 32) {
        gload_lds16(gA, lA0);
        gload_lds16(gA + half, lA1);
        gload_lds16(gB, lB0);
        gload_lds16(gB + half, lB1);
        gA += 32; gB += 32;
        __syncthreads();

        bf16x8 af[4], bf[4];
#pragma unroll
        for (int t = 0; t < 4; ++t)
            af[t] = *(const bf16x8*)(Asm + (wr + t * 16 + lrow) * 32 + quad * 8);
#pragma unroll
        for (int t = 0; t < 4; ++t)
            bf[t] = *(const bf16x8*)(Bsm + (wc + t * 16 + lrow) * 32 + quad * 8);

#pragma unroll
        for (int ti = 0; ti < 4; ++ti)
#pragma unroll
            for (int tj = 0; tj < 4; ++tj)
                acc[ti][tj] = __builtin_amdgcn_mfma_f32_16x16x32_bf16(
                    af[ti], bf[tj], acc[ti][tj], 0, 0, 0);
        __syncthreads();
    }

#pragma unroll
    for (int ti = 0; ti < 4; ++ti) {
#pragma unroll
        for (int tj = 0; tj < 4; ++tj) {
            int col = col0 + wc + tj * 16 + lrow;
#pragma unroll
            for (int r = 0; r < 4; ++r) {
                int row = row0 + wr + ti * 16 + quad * 4 + r;
                C[(size_t)row * N + col] = acc[ti][tj][r];
            }
        }
    }
}

// ---------------------------------------------------------------------------
// fp32 -> bf16 cast (vectorized 4/thread).
// ---------------------------------------------------------------------------
__global__ __launch_bounds__(256) void cast_bf16_kernel(
    const float* __restrict__ src, __bf16* __restrict__ dst, long n)
{
    long i = ((long)blockIdx.x * 256 + threadIdx.x) * 4;
    if (i >= n) return;
    float4 v = *(const float4*)(src + i);
    bf16x4 o = {(__bf16)v.x, (__bf16)v.y, (__bf16)v.z, (__bf16)v.w};
    *(bf16x4*)(dst + i) = o;
}

// ---------------------------------------------------------------------------
// Transpose-cast: src fp32 [R,Cc] -> dst bf16 [Cc,R]. R,Cc multiples of 32.
// ---------------------------------------------------------------------------
__global__ __launch_bounds__(256) void transpose_cast(
    const float* __restrict__ src, __bf16* __restrict__ dst, int R, int Cc)
{
    __shared__ float tile[32][33];
    int c0 = blockIdx.x * 32, r0 = blockIdx.y * 32;
    int tx = threadIdx.x, ty = threadIdx.y;   // 32 x 8
#pragma unroll
    for (int i = 0; i < 32; i += 8)
        tile[ty + i][tx] = src[(size_t)(r0 + ty + i) * Cc + c0 + tx];
    __syncthreads();
#pragma unroll
    for (int i = 0; i < 32; i += 8)
        dst[(size_t)(c0 + ty + i) * R + r0 + tx] = (__bf16)tile[tx][ty + i];
}

// ---------------------------------------------------------------------------
// Split-K GEMM for x_dbl: A[4096,2048] fp32 * W[2048,96] -> partials.
// Block: 64 rows x 96 cols x KC=128 K-chunk; grid (M/64, KSPLIT).
// Thread micro-tile 4x6. Partials into dead xb half of xz via part_off.
// ---------------------------------------------------------------------------
__global__ __launch_bounds__(256) void gemm_xdbl_split(
    const float* __restrict__ A,     // [BL, DINNER]
    const float* __restrict__ W,     // [DINNER, 96]
    float* __restrict__ xzbuf)       // partials region
{
    __shared__ float As[16][65];
    __shared__ float Bs[16][97];

    const int tid  = threadIdx.x;
    const int row0 = blockIdx.x * 64;
    const int kz   = blockIdx.y;
    const int kbeg = kz * KC;

    const int tr = tid >> 4;        // 0..15 (row group of 4)
    const int tc = tid & 15;        // 0..15 (col group of 6)

    const int arow = tid >> 2;          // 0..63
    const int akq  = (tid & 3) * 4;     // 0,4,8,12
    const int brow = tid >> 4;          // 0..15
    const int bcol = (tid & 15) * 6;    // 0..90

    float acc[4][6] = {};

    for (int k0 = kbeg; k0 < kbeg + KC; k0 += 16) {
        // A tile 64x16 via float4
        {
            float4 v = *(const float4*)(A + (size_t)(row0 + arow) * DINNER + k0 + akq);
            As[akq + 0][arow] = v.x;
            As[akq + 1][arow] = v.y;
            As[akq + 2][arow] = v.z;
            As[akq + 3][arow] = v.w;
        }
        // B tile 16x96
#pragma unroll
        for (int j = 0; j < 6; ++j)
            Bs[brow][bcol + j] = W[(size_t)(k0 + brow) * XDBL_N + bcol + j];
        __syncthreads();

#pragma unroll
        for (int kk = 0; kk < 16; ++kk) {
            float a[4], b[6];
#pragma unroll
            for (int i = 0; i < 4; ++i) a[i] = As[kk][tr * 4 + i];
#pragma unroll
            for (int j = 0; j < 6; ++j) b[j] = Bs[kk][tc * 6 + j];
#pragma unroll
            for (int i = 0; i < 4; ++i)
#pragma unroll
                for (int j = 0; j < 6; ++j)
                    acc[i][j] += a[i] * b[j];
        }
        __syncthreads();
    }

    const long base = (long)kz * BL * XDBL_N;
#pragma unroll
    for (int i = 0; i < 4; ++i) {
        long rowoff = base + (long)(row0 + tr * 4 + i) * XDBL_N + tc * 6;
#pragma unroll
        for (int j = 0; j < 6; ++j)
            xzbuf[part_off(rowoff + j)] = acc[i][j];
    }
}

// Reduce KSPLIT partials -> xdbl [BL, 96].
__global__ __launch_bounds__(256) void xdbl_reduce(
    const float* __restrict__ xzbuf, float* __restrict__ xdbl)
{
    long i = (long)blockIdx.x * 256 + threadIdx.x;   // < BL*96
    float s = 0.f;
#pragma unroll
    for (int kz = 0; kz < KSPLIT; ++kz)
        s += xzbuf[part_off((long)kz * BL * XDBL_N + i)];
    xdbl[i] = s;
}

// ---------------------------------------------------------------------------
// Tiled vector GEMM (step 4): C = A*B fp32, softplus epilogue.
// ---------------------------------------------------------------------------
template <int EPI>
__global__ __launch_bounds__(256) void gemm_tiled(
    const float* __restrict__ A, int lda,
    const float* __restrict__ B, int ldb,
    float* __restrict__ C, int ldc,
    int M, int N, int K,
    const float* __restrict__ bias)
{
    __shared__ float As[16][64 + 1];
    __shared__ float Bs[16][64 + 1];

    const int tid = threadIdx.x;
    const int row0 = blockIdx.y * 64;
    const int col0 = blockIdx.x * 64;
    const int tr = tid >> 4;
    const int tc = tid & 15;

    const int arow = tid >> 2;
    const int acol = (tid & 3) * 4;
    const int brow = tid >> 4;
    const int bcol = (tid & 15) * 4;

    float acc[4][4] = {};

    for (int k0 = 0; k0 < K; k0 += 16) {
#pragma unroll
        for (int j = 0; j < 4; ++j) {
            int gr = row0 + arow, gc = k0 + acol + j;
            float v = 0.f;
            if (gr < M && gc < K) v = A[(long)gr * lda + gc];
            As[acol + j][arow] = v;
        }
#pragma unroll
        for (int j = 0; j < 4; ++j) {
            int gr = k0 + brow, gc = col0 + bcol + j;
            float v = 0.f;
            if (gr < K && gc < N) v = B[(long)gr * ldb + gc];
            Bs[brow][bcol + j] = v;
        }
        __syncthreads();
#pragma unroll
        for (int kk = 0; kk < 16; ++kk) {
            float a[4], b[4];
#pragma unroll
            for (int i = 0; i < 4; ++i) a[i] = As[kk][tr * 4 + i];
#pragma unroll
            for (int j = 0; j < 4; ++j) b[j] = Bs[kk][tc * 4 + j];
#pragma unroll
            for (int i = 0; i < 4; ++i)
#pragma unroll
                for (int j = 0; j < 4; ++j)
                    acc[i][j] += a[i] * b[j];
        }
        __syncthreads();
    }

#pragma unroll
    for (int i = 0; i < 4; ++i) {
        int gr = row0 + tr * 4 + i;
        if (gr >= M) continue;
#pragma unroll
        for (int j = 0; j < 4; ++j) {
            int gc = col0 + tc * 4 + j;
            if (gc >= N) continue;
            float v = acc[i][j];
            if (EPI == 1) {
                v += bias[gc];
                v = (v > 20.f) ? v : log1pf(__expf(v));
            }
            C[(long)gr * ldc + gc] = v;
        }
    }
}

// ---------------------------------------------------------------------------
// Causal depthwise conv (d_conv=4) + SiLU.
// ---------------------------------------------------------------------------
__global__ __launch_bounds__(256) void conv_silu_kernel(
    const float* __restrict__ xz,
    const float* __restrict__ cw,
    const float* __restrict__ cb,
    float* __restrict__ xc)
{
    long i = (long)blockIdx.x * blockDim.x + threadIdx.x;
    if (i >= (long)BL * DINNER) return;
    long r = i / DINNER;
    int d = (int)(i % DINNER);
    int t = (int)(r % SEQLEN);

    float acc = cb[d];
#pragma unroll
    for (int k = 0; k < DCONV; ++k) {
        int tt = t - (DCONV - 1) + k;
        if (tt >= 0)
            acc += xz[(r - (DCONV - 1) + k) * NXZ + d] * cw[d * DCONV + k];
    }
    xc[i] = silu_f(acc);
}

// ---------------------------------------------------------------------------
// Chunked parallel scan. Summaries in dead xb half of xz:
//   hloc(b,c,n) at row (b*NCHUNK+c)*16+n;  P/hstart at row 1024 + same.
// ---------------------------------------------------------------------------
__global__ __launch_bounds__(256) void scan_pass1(
    const float* __restrict__ dt,
    const float* __restrict__ xc,
    const float* __restrict__ xdbl,
    const float* __restrict__ A_log,
    float* __restrict__ sums)
{
    const int d  = blockIdx.x * 256 + threadIdx.x;
    const int bc = blockIdx.y;
    const int b  = bc / NCHUNK, c = bc % NCHUNK;
    const long r0 = (long)b * SEQLEN + (long)c * LCH;

    float Ad[DSTATE];
    {
        const float4* al = (const float4*)(A_log + d * DSTATE);
#pragma unroll
        for (int q = 0; q < 4; ++q) {
            float4 v = al[q];
            Ad[q * 4 + 0] = -__expf(v.x); Ad[q * 4 + 1] = -__expf(v.y);
            Ad[q * 4 + 2] = -__expf(v.z); Ad[q * 4 + 3] = -__expf(v.w);
        }
    }

    float h[DSTATE] = {};
    float Pp[DSTATE];
#pragma unroll
    for (int n = 0; n < DSTATE; ++n) Pp[n] = 1.f;

    for (int t = 0; t < LCH; ++t) {
        long r = r0 + t;
        float dtv = dt[r * DINNER + d];
        float xv  = xc[r * DINNER + d];
        float xdt = xv * dtv;
        const float4* bv = (const float4*)(xdbl + r * XDBL_N + DTRANK);
        float4 B0 = bv[0], B1 = bv[1], B2 = bv[2], B3 = bv[3];
        const float Bn[DSTATE] = {B0.x,B0.y,B0.z,B0.w, B1.x,B1.y,B1.z,B1.w,
                                  B2.x,B2.y,B2.z,B2.w, B3.x,B3.y,B3.z,B3.w};
#pragma unroll
        for (int n = 0; n < DSTATE; ++n) {
            float dA = __expf(Ad[n] * dtv);
            h[n] = h[n] * dA + xdt * Bn[n];
            Pp[n] *= dA;
        }
    }

    const long rowbase = (long)bc * DSTATE;
#pragma unroll
    for (int n = 0; n < DSTATE; ++n) {
        sums[(rowbase + n) * NXZ + d] = h[n];
        sums[(1024 + rowbase + n) * NXZ + d] = Pp[n];
    }
}

__global__ __launch_bounds__(256) void scan_combine(float* __restrict__ sums)
{
    int u = blockIdx.x * 256 + threadIdx.x;
    int d = u & (DINNER - 1);
    int n = (u >> 11) & (DSTATE - 1);
    int b = u >> 15;
    float hg = 0.f;
    for (int c = 0; c < NCHUNK; ++c) {
        long row = (long)(b * NCHUNK + c) * DSTATE + n;
        float p  = sums[(1024 + row) * NXZ + d];
        float hl = sums[row * NXZ + d];
        sums[(1024 + row) * NXZ + d] = hg;
        hg = p * hg + hl;
    }
}

// Pass 3: replay from hstart, fused gate, emit bf16 gated activation.
__global__ __launch_bounds__(256) void scan_pass3(
    const float* __restrict__ dt,
    const float* __restrict__ xc,
    const float* __restrict__ xdbl,
    const float* __restrict__ A_log,
    const float* __restrict__ xz,     // z half + hstart rows
    const float* __restrict__ Dp,
    __bf16* __restrict__ gated)       // [BL, DINNER] bf16
{
    const int d  = blockIdx.x * 256 + threadIdx.x;
    const int bc = blockIdx.y;
    const int b  = bc / NCHUNK, c = bc % NCHUNK;
    const long r0 = (long)b * SEQLEN + (long)c * LCH;

    float Ad[DSTATE];
    {
        const float4* al = (const float4*)(A_log + d * DSTATE);
#pragma unroll
        for (int q = 0; q < 4; ++q) {
            float4 v = al[q];
            Ad[q * 4 + 0] = -__expf(v.x); Ad[q * 4 + 1] = -__expf(v.y);
            Ad[q * 4 + 2] = -__expf(v.z); Ad[q * 4 + 3] = -__expf(v.w);
        }
    }

    float h[DSTATE];
    const long rowbase = (long)bc * DSTATE;
#pragma unroll
    for (int n = 0; n < DSTATE; ++n)
        h[n] = xz[(1024 + rowbase + n) * NXZ + d];

    const float Dv = Dp[d];

    for (int t = 0; t < LCH; ++t) {
        long r = r0 + t;
        float dtv = dt[r * DINNER + d];
        float xv  = xc[r * DINNER + d];
        float xdt = xv * dtv;
        const float4* bv = (const float4*)(xdbl + r * XDBL_N + DTRANK);
        float4 B0 = bv[0], B1 = bv[1], B2 = bv[2], B3 = bv[3];
        float4 C0 = bv[4], C1 = bv[5], C2 = bv[6], C3 = bv[7];
        const float Bn[DSTATE] = {B0.x,B0.y,B0.z,B0.w, B1.x,B1.y,B1.z,B1.w,
                                  B2.x,B2.y,B2.z,B2.w, B3.x,B3.y,B3.z,B3.w};
        const float Cn[DSTATE] = {C0.x,C0.y,C0.z,C0.w, C1.x,C1.y,C1.z,C1.w,
                                  C2.x,C2.y,C2.z,C2.w, C3.x,C3.y,C3.z,C3.w};
        float y = 0.f;
#pragma unroll
        for (int n = 0; n < DSTATE; ++n) {
            float dA = __expf(Ad[n] * dtv);
            h[n] = h[n] * dA + xdt * Bn[n];
            y += h[n] * Cn[n];
        }
        float z = xz[r * NXZ + DINNER + d];
        float yy = y + xv * Dv;
        gated[r * DINNER + d] = (__bf16)(yy * silu_f(z));
    }
}

// ---------------------------------------------------------------------------
extern "C" void kernel_launch(void* const* d_in, const int* in_sizes, int n_in,
                              void* d_out, int out_size, void* d_ws, size_t ws_size,
                              hipStream_t stream) {
    const float* x      = (const float*)d_in[0];  // [B,L,DMODEL]
    const float* W_in   = (const float*)d_in[1];  // [DMODEL, NXZ]
    const float* conv_w = (const float*)d_in[2];  // [DINNER, 4]
    const float* conv_b = (const float*)d_in[3];  // [DINNER]
    const float* W_x    = (const float*)d_in[4];  // [DINNER, 96]
    const float* W_dt   = (const float*)d_in[5];  // [DTRANK, DINNER]
    const float* b_dt   = (const float*)d_in[6];  // [DINNER]
    const float* A_log  = (const float*)d_in[7];  // [DINNER, 16]
    const float* Dp     = (const float*)d_in[8];  // [DINNER]
    const float* W_out  = (const float*)d_in[9];  // [DINNER, DMODEL]
    float* out = (float*)d_out;                   // [B,L,DMODEL]

    float* ws = (float*)d_ws;
    float* xz   = ws;                                   // 16.78M floats
    float* xc   = xz + (long)BL * NXZ;                  //  8.39M
    float* xdbl = xc + (long)BL * DINNER;               //  0.39M
    float* dt   = xdbl + (long)BL * XDBL_N;             //  8.39M
    __bf16* gated16 = (__bf16*)(dt + (long)BL * DINNER);        // 8.39M bf16
    __bf16* WoT16   = (__bf16*)((float*)gated16 + (long)BL * DINNER / 2); // 2.10M bf16
    // xb16 / W_inT16 alias the xc region (dead until conv)
    __bf16* xb16  = (__bf16*)xc;                        // 4.19M bf16
    __bf16* WiT16 = (__bf16*)(xc + (long)BL * DMODEL / 2); // 4.19M bf16
    // total ws ~157 MB (split-K partials + scan summaries reuse dead xb half of xz)

    dim3 blk(256);

    // 0) casts: x -> bf16; W_in -> bf16^T; W_out -> bf16^T
    cast_bf16_kernel<<<dim3((BL * DMODEL / 4) / 256), blk, 0, stream>>>(
        x, xb16, (long)BL * DMODEL);
    transpose_cast<<<dim3(NXZ / 32, DMODEL / 32), dim3(32, 8), 0, stream>>>(
        W_in, WiT16, DMODEL, NXZ);
    transpose_cast<<<dim3(DMODEL / 32, DINNER / 32), dim3(32, 8), 0, stream>>>(
        W_out, WoT16, DINNER, DMODEL);

    // 1) xz = x @ W_in   (MFMA bf16)
    gemm_bt_mfma<<<dim3(NXZ / 128, BL / 128), blk, 0, stream>>>(
        xb16, WiT16, xz, BL, NXZ, DMODEL);

    // 2) causal depthwise conv + silu -> xc (overwrites xb16/WiT16 — dead now)
    {
        long total = (long)BL * DINNER;
        conv_silu_kernel<<<dim3((unsigned)((total + 255) / 256)), blk, 0, stream>>>(
            xz, conv_w, conv_b, xc);
    }
    // 3) x_dbl = xc @ W_x   (split-K into dead xb half of xz, then reduce)
    gemm_xdbl_split<<<dim3(BL / 64, KSPLIT), blk, 0, stream>>>(xc, W_x, xz);
    xdbl_reduce<<<dim3((BL * XDBL_N) / 256), blk, 0, stream>>>(xz, xdbl);

    // 4) dt = softplus(x_dbl[:, :64] @ W_dt + b_dt)
    gemm_tiled<1><<<dim3(DINNER / 64, BL / 64), blk, 0, stream>>>(
        xdbl, XDBL_N, W_dt, DINNER, dt, DINNER, BL, DINNER, DTRANK, b_dt);

    // 5) chunked scan: pass1 -> combine -> pass3 (+fused gate, bf16 out)
    {
        dim3 grid1(DINNER / 256, BATCH * NCHUNK);
        scan_pass1<<<grid1, blk, 0, stream>>>(dt, xc, xdbl, A_log, xz);
        scan_combine<<<dim3((BATCH * DSTATE * DINNER) / 256), blk, 0, stream>>>(xz);
        scan_pass3<<<grid1, blk, 0, stream>>>(dt, xc, xdbl, A_log, xz, Dp, gated16);
    }
    // 7) out = gated @ W_out   (MFMA bf16)
    gemm_bt_mfma<<<dim3(DMODEL / 128, BL / 128), blk, 0, stream>>>(
        gated16, WoT16, out, BL, DMODEL, DINNER);

    (void)in_sizes; (void)n_in; (void)out_size; (void)ws_size;
}

// Round 6
// 424.528 us; speedup vs baseline: 8.1293x; 1.0132x over previous
//
#include <hip/hip_runtime.h>
#include <hip/hip_bf16.h>

// Problem constants (MambaBlock): B=2, L=2048, d_model=1024, d_inner=2048,
// d_conv=4, dt_rank=64, d_state=16. All inputs/output float32 (per reference).

#define BATCH   2
#define SEQLEN  2048
#define DMODEL  1024
#define DINNER  2048
#define DCONV   4
#define DTRANK  64
#define DSTATE  16
#define BL      (BATCH * SEQLEN)         // 4096
#define NXZ     (2 * DINNER)             // 4096
#define XDBL_N  (DTRANK + 2 * DSTATE)    // 96
#define LCH     64                       // chunk length for parallel scan
#define NCHUNK  (SEQLEN / LCH)           // 32 chunks per sequence
#define KSPLIT  16                       // split-K for the x_dbl GEMM
#define KC      (DINNER / KSPLIT)        // 128

typedef __bf16 bf16x8 __attribute__((ext_vector_type(8)));
typedef __bf16 bf16x4 __attribute__((ext_vector_type(4)));
typedef float  floatx4 __attribute__((ext_vector_type(4)));

__device__ __forceinline__ float silu_f(float v) {
    return v / (1.f + __expf(-v));
}

__device__ __forceinline__ void gload_lds16(const __bf16* g, __bf16* l) {
    __builtin_amdgcn_global_load_lds(
        (const __attribute__((address_space(1))) void*)g,
        (__attribute__((address_space(3))) void*)l, 16, 0, 0);
}

// Partials for split-K x_dbl live in the dead xb half of xz:
// flat pidx -> xz[(pidx>>11) * NXZ + (pidx & 2047)], pidx < 16*4096*96 = 6.3M
__device__ __forceinline__ long part_off(long pidx) {
    return (pidx >> 11) * NXZ + (pidx & 2047);
}

// ---------------------------------------------------------------------------
// MFMA bf16 GEMM (m97 structure): C[M,N] = A[M,K] * B[K,N], fp32 out.
// A [M,K] bf16 row-major; BT [N,K] bf16 row-major.
// EPI: 0 = plain fp32 store; 1 = softplus(acc + bias[col]) fp32 store.
// ---------------------------------------------------------------------------
template <int EPI>
__global__ __launch_bounds__(256) void gemm_bt_mfma(
    const __bf16* __restrict__ A,
    const __bf16* __restrict__ BT,
    float* __restrict__ C,
    int M, int N, int K,
    const float* __restrict__ bias)
{
    __shared__ __bf16 Asm[128 * 32];
    __shared__ __bf16 Bsm[128 * 32];

    const int tid  = threadIdx.x;
    const int w    = tid >> 6;
    const int lane = tid & 63;
    const int lrow = lane & 15;
    const int quad = lane >> 4;
    const int row0 = blockIdx.y * 128;
    const int col0 = blockIdx.x * 128;
    const int wr   = (w >> 1) * 64;
    const int wc   = (w & 1) * 64;

    const int ldr = tid >> 2;
    const int ldk = (tid & 3) * 8;
    const __bf16* gA = A  + (size_t)(row0 + ldr) * K + ldk;
    const __bf16* gB = BT + (size_t)(col0 + ldr) * K + ldk;
    const size_t half = (size_t)64 * K;
    __bf16* lA0 = Asm + w * 512;
    __bf16* lA1 = Asm + 2048 + w * 512;
    __bf16* lB0 = Bsm + w * 512;
    __bf16* lB1 = Bsm + 2048 + w * 512;

    floatx4 acc[4][4];
#pragma unroll
    for (int i = 0; i < 4; ++i)
#pragma unroll
        for (int j = 0; j < 4; ++j)
            acc[i][j] = (floatx4){0.f, 0.f, 0.f, 0.f};

    for (int k0 = 0; k0 < K; k0 += 32) {
        gload_lds16(gA, lA0);
        gload_lds16(gA + half, lA1);
        gload_lds16(gB, lB0);
        gload_lds16(gB + half, lB1);
        gA += 32; gB += 32;
        __syncthreads();

        bf16x8 af[4], bf[4];
#pragma unroll
        for (int t = 0; t < 4; ++t)
            af[t] = *(const bf16x8*)(Asm + (wr + t * 16 + lrow) * 32 + quad * 8);
#pragma unroll
        for (int t = 0; t < 4; ++t)
            bf[t] = *(const bf16x8*)(Bsm + (wc + t * 16 + lrow) * 32 + quad * 8);

#pragma unroll
        for (int ti = 0; ti < 4; ++ti)
#pragma unroll
            for (int tj = 0; tj < 4; ++tj)
                acc[ti][tj] = __builtin_amdgcn_mfma_f32_16x16x32_bf16(
                    af[ti], bf[tj], acc[ti][tj], 0, 0, 0);
        __syncthreads();
    }

#pragma unroll
    for (int ti = 0; ti < 4; ++ti) {
#pragma unroll
        for (int tj = 0; tj < 4; ++tj) {
            int col = col0 + wc + tj * 16 + lrow;
            float bv = (EPI == 1) ? bias[col] : 0.f;
#pragma unroll
            for (int r = 0; r < 4; ++r) {
                int row = row0 + wr + ti * 16 + quad * 4 + r;
                float v = acc[ti][tj][r];
                if (EPI == 1) {
                    v += bv;
                    v = (v > 20.f) ? v : log1pf(__expf(v));
                }
                C[(size_t)row * N + col] = v;
            }
        }
    }
}

// ---------------------------------------------------------------------------
// fp32 -> bf16 cast (vectorized 4/thread).
// ---------------------------------------------------------------------------
__global__ __launch_bounds__(256) void cast_bf16_kernel(
    const float* __restrict__ src, __bf16* __restrict__ dst, long n)
{
    long i = ((long)blockIdx.x * 256 + threadIdx.x) * 4;
    if (i >= n) return;
    float4 v = *(const float4*)(src + i);
    bf16x4 o = {(__bf16)v.x, (__bf16)v.y, (__bf16)v.z, (__bf16)v.w};
    *(bf16x4*)(dst + i) = o;
}

// ---------------------------------------------------------------------------
// Transpose-cast: src fp32 [R,Cc] -> dst bf16 [Cc,R]. R,Cc multiples of 32.
// ---------------------------------------------------------------------------
__global__ __launch_bounds__(256) void transpose_cast(
    const float* __restrict__ src, __bf16* __restrict__ dst, int R, int Cc)
{
    __shared__ float tile[32][33];
    int c0 = blockIdx.x * 32, r0 = blockIdx.y * 32;
    int tx = threadIdx.x, ty = threadIdx.y;   // 32 x 8
#pragma unroll
    for (int i = 0; i < 32; i += 8)
        tile[ty + i][tx] = src[(size_t)(r0 + ty + i) * Cc + c0 + tx];
    __syncthreads();
#pragma unroll
    for (int i = 0; i < 32; i += 8)
        dst[(size_t)(c0 + ty + i) * R + r0 + tx] = (__bf16)tile[tx][ty + i];
}

// ---------------------------------------------------------------------------
// Split-K GEMM for x_dbl: A[4096,2048] fp32 * W[2048,96] -> partials.
// ---------------------------------------------------------------------------
__global__ __launch_bounds__(256) void gemm_xdbl_split(
    const float* __restrict__ A,     // [BL, DINNER]
    const float* __restrict__ W,     // [DINNER, 96]
    float* __restrict__ xzbuf)       // partials region
{
    __shared__ float As[16][65];
    __shared__ float Bs[16][97];

    const int tid  = threadIdx.x;
    const int row0 = blockIdx.x * 64;
    const int kz   = blockIdx.y;
    const int kbeg = kz * KC;

    const int tr = tid >> 4;
    const int tc = tid & 15;

    const int arow = tid >> 2;
    const int akq  = (tid & 3) * 4;
    const int brow = tid >> 4;
    const int bcol = (tid & 15) * 6;

    float acc[4][6] = {};

    for (int k0 = kbeg; k0 < kbeg + KC; k0 += 16) {
        {
            float4 v = *(const float4*)(A + (size_t)(row0 + arow) * DINNER + k0 + akq);
            As[akq + 0][arow] = v.x;
            As[akq + 1][arow] = v.y;
            As[akq + 2][arow] = v.z;
            As[akq + 3][arow] = v.w;
        }
#pragma unroll
        for (int j = 0; j < 6; ++j)
            Bs[brow][bcol + j] = W[(size_t)(k0 + brow) * XDBL_N + bcol + j];
        __syncthreads();

#pragma unroll
        for (int kk = 0; kk < 16; ++kk) {
            float a[4], b[6];
#pragma unroll
            for (int i = 0; i < 4; ++i) a[i] = As[kk][tr * 4 + i];
#pragma unroll
            for (int j = 0; j < 6; ++j) b[j] = Bs[kk][tc * 6 + j];
#pragma unroll
            for (int i = 0; i < 4; ++i)
#pragma unroll
                for (int j = 0; j < 6; ++j)
                    acc[i][j] += a[i] * b[j];
        }
        __syncthreads();
    }

    const long base = (long)kz * BL * XDBL_N;
#pragma unroll
    for (int i = 0; i < 4; ++i) {
        long rowoff = base + (long)(row0 + tr * 4 + i) * XDBL_N + tc * 6;
#pragma unroll
        for (int j = 0; j < 6; ++j)
            xzbuf[part_off(rowoff + j)] = acc[i][j];
    }
}

// Reduce KSPLIT partials -> xdbl [BL, 96]; cols<64 additionally stored as
// bf16 dt_low [BL, 64] (A operand of the dt MFMA GEMM).
__global__ __launch_bounds__(256) void xdbl_reduce(
    const float* __restrict__ xzbuf, float* __restrict__ xdbl,
    __bf16* __restrict__ dtlow16)
{
    long i = (long)blockIdx.x * 256 + threadIdx.x;   // < BL*96
    float s = 0.f;
#pragma unroll
    for (int kz = 0; kz < KSPLIT; ++kz)
        s += xzbuf[part_off((long)kz * BL * XDBL_N + i)];
    xdbl[i] = s;
    int col = (int)(i % XDBL_N);
    if (col < DTRANK) {
        long row = i / XDBL_N;
        dtlow16[row * DTRANK + col] = (__bf16)s;
    }
}

// ---------------------------------------------------------------------------
// Causal depthwise conv (d_conv=4) + SiLU.
// ---------------------------------------------------------------------------
__global__ __launch_bounds__(256) void conv_silu_kernel(
    const float* __restrict__ xz,
    const float* __restrict__ cw,
    const float* __restrict__ cb,
    float* __restrict__ xc)
{
    long i = (long)blockIdx.x * blockDim.x + threadIdx.x;
    if (i >= (long)BL * DINNER) return;
    long r = i / DINNER;
    int d = (int)(i % DINNER);
    int t = (int)(r % SEQLEN);

    float acc = cb[d];
#pragma unroll
    for (int k = 0; k < DCONV; ++k) {
        int tt = t - (DCONV - 1) + k;
        if (tt >= 0)
            acc += xz[(r - (DCONV - 1) + k) * NXZ + d] * cw[d * DCONV + k];
    }
    xc[i] = silu_f(acc);
}

// ---------------------------------------------------------------------------
// Chunked parallel scan. Summaries in dead xb half of xz:
//   hloc(b,c,n) at row (b*NCHUNK+c)*16+n;  P/hstart at row 1024 + same.
// ---------------------------------------------------------------------------
__global__ __launch_bounds__(256) void scan_pass1(
    const float* __restrict__ dt,
    const float* __restrict__ xc,
    const float* __restrict__ xdbl,
    const float* __restrict__ A_log,
    float* __restrict__ sums)
{
    const int d  = blockIdx.x * 256 + threadIdx.x;
    const int bc = blockIdx.y;
    const int b  = bc / NCHUNK, c = bc % NCHUNK;
    const long r0 = (long)b * SEQLEN + (long)c * LCH;

    float Ad[DSTATE];
    {
        const float4* al = (const float4*)(A_log + d * DSTATE);
#pragma unroll
        for (int q = 0; q < 4; ++q) {
            float4 v = al[q];
            Ad[q * 4 + 0] = -__expf(v.x); Ad[q * 4 + 1] = -__expf(v.y);
            Ad[q * 4 + 2] = -__expf(v.z); Ad[q * 4 + 3] = -__expf(v.w);
        }
    }

    float h[DSTATE] = {};
    float Pp[DSTATE];
#pragma unroll
    for (int n = 0; n < DSTATE; ++n) Pp[n] = 1.f;

    for (int t = 0; t < LCH; ++t) {
        long r = r0 + t;
        float dtv = dt[r * DINNER + d];
        float xv  = xc[r * DINNER + d];
        float xdt = xv * dtv;
        const float4* bv = (const float4*)(xdbl + r * XDBL_N + DTRANK);
        float4 B0 = bv[0], B1 = bv[1], B2 = bv[2], B3 = bv[3];
        const float Bn[DSTATE] = {B0.x,B0.y,B0.z,B0.w, B1.x,B1.y,B1.z,B1.w,
                                  B2.x,B2.y,B2.z,B2.w, B3.x,B3.y,B3.z,B3.w};
#pragma unroll
        for (int n = 0; n < DSTATE; ++n) {
            float dA = __expf(Ad[n] * dtv);
            h[n] = h[n] * dA + xdt * Bn[n];
            Pp[n] *= dA;
        }
    }

    const long rowbase = (long)bc * DSTATE;
#pragma unroll
    for (int n = 0; n < DSTATE; ++n) {
        sums[(rowbase + n) * NXZ + d] = h[n];
        sums[(1024 + rowbase + n) * NXZ + d] = Pp[n];
    }
}

__global__ __launch_bounds__(256) void scan_combine(float* __restrict__ sums)
{
    int u = blockIdx.x * 256 + threadIdx.x;
    int d = u & (DINNER - 1);
    int n = (u >> 11) & (DSTATE - 1);
    int b = u >> 15;
    float hg = 0.f;
    for (int c = 0; c < NCHUNK; ++c) {
        long row = (long)(b * NCHUNK + c) * DSTATE + n;
        float p  = sums[(1024 + row) * NXZ + d];
        float hl = sums[row * NXZ + d];
        sums[(1024 + row) * NXZ + d] = hg;
        hg = p * hg + hl;
    }
}

// Pass 3: replay from hstart, fused gate, emit bf16 gated activation.
__global__ __launch_bounds__(256) void scan_pass3(
    const float* __restrict__ dt,
    const float* __restrict__ xc,
    const float* __restrict__ xdbl,
    const float* __restrict__ A_log,
    const float* __restrict__ xz,     // z half + hstart rows
    const float* __restrict__ Dp,
    __bf16* __restrict__ gated)       // [BL, DINNER] bf16
{
    const int d  = blockIdx.x * 256 + threadIdx.x;
    const int bc = blockIdx.y;
    const int b  = bc / NCHUNK, c = bc % NCHUNK;
    const long r0 = (long)b * SEQLEN + (long)c * LCH;

    float Ad[DSTATE];
    {
        const float4* al = (const float4*)(A_log + d * DSTATE);
#pragma unroll
        for (int q = 0; q < 4; ++q) {
            float4 v = al[q];
            Ad[q * 4 + 0] = -__expf(v.x); Ad[q * 4 + 1] = -__expf(v.y);
            Ad[q * 4 + 2] = -__expf(v.z); Ad[q * 4 + 3] = -__expf(v.w);
        }
    }

    float h[DSTATE];
    const long rowbase = (long)bc * DSTATE;
#pragma unroll
    for (int n = 0; n < DSTATE; ++n)
        h[n] = xz[(1024 + rowbase + n) * NXZ + d];

    const float Dv = Dp[d];

    for (int t = 0; t < LCH; ++t) {
        long r = r0 + t;
        float dtv = dt[r * DINNER + d];
        float xv  = xc[r * DINNER + d];
        float xdt = xv * dtv;
        const float4* bv = (const float4*)(xdbl + r * XDBL_N + DTRANK);
        float4 B0 = bv[0], B1 = bv[1], B2 = bv[2], B3 = bv[3];
        float4 C0 = bv[4], C1 = bv[5], C2 = bv[6], C3 = bv[7];
        const float Bn[DSTATE] = {B0.x,B0.y,B0.z,B0.w, B1.x,B1.y,B1.z,B1.w,
                                  B2.x,B2.y,B2.z,B2.w, B3.x,B3.y,B3.z,B3.w};
        const float Cn[DSTATE] = {C0.x,C0.y,C0.z,C0.w, C1.x,C1.y,C1.z,C1.w,
                                  C2.x,C2.y,C2.z,C2.w, C3.x,C3.y,C3.z,C3.w};
        float y = 0.f;
#pragma unroll
        for (int n = 0; n < DSTATE; ++n) {
            float dA = __expf(Ad[n] * dtv);
            h[n] = h[n] * dA + xdt * Bn[n];
            y += h[n] * Cn[n];
        }
        float z = xz[r * NXZ + DINNER + d];
        float yy = y + xv * Dv;
        gated[r * DINNER + d] = (__bf16)(yy * silu_f(z));
    }
}

// ---------------------------------------------------------------------------
extern "C" void kernel_launch(void* const* d_in, const int* in_sizes, int n_in,
                              void* d_out, int out_size, void* d_ws, size_t ws_size,
                              hipStream_t stream) {
    const float* x      = (const float*)d_in[0];  // [B,L,DMODEL]
    const float* W_in   = (const float*)d_in[1];  // [DMODEL, NXZ]
    const float* conv_w = (const float*)d_in[2];  // [DINNER, 4]
    const float* conv_b = (const float*)d_in[3];  // [DINNER]
    const float* W_x    = (const float*)d_in[4];  // [DINNER, 96]
    const float* W_dt   = (const float*)d_in[5];  // [DTRANK, DINNER]
    const float* b_dt   = (const float*)d_in[6];  // [DINNER]
    const float* A_log  = (const float*)d_in[7];  // [DINNER, 16]
    const float* Dp     = (const float*)d_in[8];  // [DINNER]
    const float* W_out  = (const float*)d_in[9];  // [DINNER, DMODEL]
    float* out = (float*)d_out;                   // [B,L,DMODEL]

    float* ws = (float*)d_ws;
    float* xz   = ws;                                   // 16.78M floats
    float* xc   = xz + (long)BL * NXZ;                  //  8.39M
    float* xdbl = xc + (long)BL * DINNER;               //  0.39M
    float* dt   = xdbl + (long)BL * XDBL_N;             //  8.39M
    __bf16* gated16 = (__bf16*)(dt + (long)BL * DINNER);              // BL*DINNER bf16
    __bf16* WoT16   = (__bf16*)((float*)gated16 + (long)BL * DINNER / 2); // DINNER*DMODEL bf16
    __bf16* WdtT16  = WoT16 + (long)DINNER * DMODEL;    // [DINNER, 64] bf16
    __bf16* dtlow16 = WdtT16 + (long)DINNER * DTRANK;   // [BL, 64] bf16
    // xb16 / W_inT16 alias the xc region (dead until conv)
    __bf16* xb16  = (__bf16*)xc;
    __bf16* WiT16 = (__bf16*)(xc + (long)BL * DMODEL / 2);
    // total ws ~158 MB

    dim3 blk(256);

    // 0) casts: x -> bf16; W_in -> bf16^T; W_out -> bf16^T; W_dt -> bf16^T
    cast_bf16_kernel<<<dim3((BL * DMODEL / 4) / 256), blk, 0, stream>>>(
        x, xb16, (long)BL * DMODEL);
    transpose_cast<<<dim3(NXZ / 32, DMODEL / 32), dim3(32, 8), 0, stream>>>(
        W_in, WiT16, DMODEL, NXZ);
    transpose_cast<<<dim3(DMODEL / 32, DINNER / 32), dim3(32, 8), 0, stream>>>(
        W_out, WoT16, DINNER, DMODEL);
    transpose_cast<<<dim3(DINNER / 32, DTRANK / 32), dim3(32, 8), 0, stream>>>(
        W_dt, WdtT16, DTRANK, DINNER);

    // 1) xz = x @ W_in   (MFMA bf16)
    gemm_bt_mfma<0><<<dim3(NXZ / 128, BL / 128), blk, 0, stream>>>(
        xb16, WiT16, xz, BL, NXZ, DMODEL, nullptr);

    // 2) causal depthwise conv + silu -> xc (overwrites xb16/WiT16 — dead now)
    {
        long total = (long)BL * DINNER;
        conv_silu_kernel<<<dim3((unsigned)((total + 255) / 256)), blk, 0, stream>>>(
            xz, conv_w, conv_b, xc);
    }
    // 3) x_dbl = xc @ W_x   (split-K into dead xb half of xz, then reduce;
    //    reduce also emits dt_low as bf16)
    gemm_xdbl_split<<<dim3(BL / 64, KSPLIT), blk, 0, stream>>>(xc, W_x, xz);
    xdbl_reduce<<<dim3((BL * XDBL_N) / 256), blk, 0, stream>>>(xz, xdbl, dtlow16);

    // 4) dt = softplus(dt_low @ W_dt + b_dt)   (MFMA bf16, K=64)
    gemm_bt_mfma<1><<<dim3(DINNER / 128, BL / 128), blk, 0, stream>>>(
        dtlow16, WdtT16, dt, BL, DINNER, DTRANK, b_dt);

    // 5) chunked scan: pass1 -> combine -> pass3 (+fused gate, bf16 out)
    {
        dim3 grid1(DINNER / 256, BATCH * NCHUNK);
        scan_pass1<<<grid1, blk, 0, stream>>>(dt, xc, xdbl, A_log, xz);
        scan_combine<<<dim3((BATCH * DSTATE * DINNER) / 256), blk, 0, stream>>>(xz);
        scan_pass3<<<grid1, blk, 0, stream>>>(dt, xc, xdbl, A_log, xz, Dp, gated16);
    }
    // 7) out = gated @ W_out   (MFMA bf16)
    gemm_bt_mfma<0><<<dim3(DMODEL / 128, BL / 128), blk, 0, stream>>>(
        gated16, WoT16, out, BL, DMODEL, DINNER, nullptr);

    (void)in_sizes; (void)n_in; (void)out_size; (void)ws_size;
}

// Round 7
// 384.549 us; speedup vs baseline: 8.9744x; 1.1040x over previous
//
#include <hip/hip_runtime.h>
#include <hip/hip_bf16.h>

// Problem constants (MambaBlock): B=2, L=2048, d_model=1024, d_inner=2048,
// d_conv=4, dt_rank=64, d_state=16. All inputs/output float32 (per reference).

#define BATCH   2
#define SEQLEN  2048
#define DMODEL  1024
#define DINNER  2048
#define DCONV   4
#define DTRANK  64
#define DSTATE  16
#define BL      (BATCH * SEQLEN)         // 4096
#define NXZ     (2 * DINNER)             // 4096
#define XDBL_N  (DTRANK + 2 * DSTATE)    // 96
#define LCH     64                       // chunk length for parallel scan
#define NCHUNK  (SEQLEN / LCH)           // 32 chunks per sequence
#define KSPLIT  16                       // split-K for the x_dbl GEMM
#define KC      (DINNER / KSPLIT)        // 128

typedef __bf16 bf16x8 __attribute__((ext_vector_type(8)));
typedef __bf16 bf16x4 __attribute__((ext_vector_type(4)));
typedef float  floatx4 __attribute__((ext_vector_type(4)));

__device__ __forceinline__ float silu_f(float v) {
    return v / (1.f + __expf(-v));
}

// Fast softplus: native v_exp_f32/v_log_f32. For v<=20, log(1+e^v); abs error
// ~1e-7 for very negative v (vs log1pf) — negligible next to bf16 noise.
__device__ __forceinline__ float softplus_f(float v) {
    return (v > 20.f) ? v : __logf(1.f + __expf(v));
}

__device__ __forceinline__ void gload_lds16(const __bf16* g, __bf16* l) {
    __builtin_amdgcn_global_load_lds(
        (const __attribute__((address_space(1))) void*)g,
        (__attribute__((address_space(3))) void*)l, 16, 0, 0);
}

// Partials for split-K x_dbl live in the dead xb half of xz:
// flat pidx -> xz[(pidx>>11) * NXZ + (pidx & 2047)], pidx < 16*4096*96 = 6.3M
__device__ __forceinline__ long part_off(long pidx) {
    return (pidx >> 11) * NXZ + (pidx & 2047);
}

// ---------------------------------------------------------------------------
// MFMA bf16 GEMM (m97 structure): C[M,N] = A[M,K] * B[K,N], fp32 out.
// A [M,K] bf16 row-major; BT [N,K] bf16 row-major.
// EPI: 0 = plain fp32 store; 1 = softplus(acc + bias[col]) fp32 store.
// ---------------------------------------------------------------------------
template <int EPI>
__global__ __launch_bounds__(256) void gemm_bt_mfma(
    const __bf16* __restrict__ A,
    const __bf16* __restrict__ BT,
    float* __restrict__ C,
    int M, int N, int K,
    const float* __restrict__ bias)
{
    __shared__ __bf16 Asm[128 * 32];
    __shared__ __bf16 Bsm[128 * 32];

    const int tid  = threadIdx.x;
    const int w    = tid >> 6;
    const int lane = tid & 63;
    const int lrow = lane & 15;
    const int quad = lane >> 4;
    const int row0 = blockIdx.y * 128;
    const int col0 = blockIdx.x * 128;
    const int wr   = (w >> 1) * 64;
    const int wc   = (w & 1) * 64;

    const int ldr = tid >> 2;
    const int ldk = (tid & 3) * 8;
    const __bf16* gA = A  + (size_t)(row0 + ldr) * K + ldk;
    const __bf16* gB = BT + (size_t)(col0 + ldr) * K + ldk;
    const size_t half = (size_t)64 * K;
    __bf16* lA0 = Asm + w * 512;
    __bf16* lA1 = Asm + 2048 + w * 512;
    __bf16* lB0 = Bsm + w * 512;
    __bf16* lB1 = Bsm + 2048 + w * 512;

    floatx4 acc[4][4];
#pragma unroll
    for (int i = 0; i < 4; ++i)
#pragma unroll
        for (int j = 0; j < 4; ++j)
            acc[i][j] = (floatx4){0.f, 0.f, 0.f, 0.f};

    for (int k0 = 0; k0 < K; k0 += 32) {
        gload_lds16(gA, lA0);
        gload_lds16(gA + half, lA1);
        gload_lds16(gB, lB0);
        gload_lds16(gB + half, lB1);
        gA += 32; gB += 32;
        __syncthreads();

        bf16x8 af[4], bf[4];
#pragma unroll
        for (int t = 0; t < 4; ++t)
            af[t] = *(const bf16x8*)(Asm + (wr + t * 16 + lrow) * 32 + quad * 8);
#pragma unroll
        for (int t = 0; t < 4; ++t)
            bf[t] = *(const bf16x8*)(Bsm + (wc + t * 16 + lrow) * 32 + quad * 8);

#pragma unroll
        for (int ti = 0; ti < 4; ++ti)
#pragma unroll
            for (int tj = 0; tj < 4; ++tj)
                acc[ti][tj] = __builtin_amdgcn_mfma_f32_16x16x32_bf16(
                    af[ti], bf[tj], acc[ti][tj], 0, 0, 0);
        __syncthreads();
    }

#pragma unroll
    for (int ti = 0; ti < 4; ++ti) {
#pragma unroll
        for (int tj = 0; tj < 4; ++tj) {
            int col = col0 + wc + tj * 16 + lrow;
            float bv = (EPI == 1) ? bias[col] : 0.f;
#pragma unroll
            for (int r = 0; r < 4; ++r) {
                int row = row0 + wr + ti * 16 + quad * 4 + r;
                float v = acc[ti][tj][r];
                if (EPI == 1) v = softplus_f(v + bv);
                C[(size_t)row * N + col] = v;
            }
        }
    }
}

// ---------------------------------------------------------------------------
// fp32 -> bf16 cast (vectorized 4/thread).
// ---------------------------------------------------------------------------
__global__ __launch_bounds__(256) void cast_bf16_kernel(
    const float* __restrict__ src, __bf16* __restrict__ dst, long n)
{
    long i = ((long)blockIdx.x * 256 + threadIdx.x) * 4;
    if (i >= n) return;
    float4 v = *(const float4*)(src + i);
    bf16x4 o = {(__bf16)v.x, (__bf16)v.y, (__bf16)v.z, (__bf16)v.w};
    *(bf16x4*)(dst + i) = o;
}

// ---------------------------------------------------------------------------
// Transpose-cast: src fp32 [R,Cc] -> dst bf16 [Cc,R]. R,Cc multiples of 32.
// ---------------------------------------------------------------------------
__global__ __launch_bounds__(256) void transpose_cast(
    const float* __restrict__ src, __bf16* __restrict__ dst, int R, int Cc)
{
    __shared__ float tile[32][33];
    int c0 = blockIdx.x * 32, r0 = blockIdx.y * 32;
    int tx = threadIdx.x, ty = threadIdx.y;   // 32 x 8
#pragma unroll
    for (int i = 0; i < 32; i += 8)
        tile[ty + i][tx] = src[(size_t)(r0 + ty + i) * Cc + c0 + tx];
    __syncthreads();
#pragma unroll
    for (int i = 0; i < 32; i += 8)
        dst[(size_t)(c0 + ty + i) * R + r0 + tx] = (__bf16)tile[tx][ty + i];
}

// ---------------------------------------------------------------------------
// Split-K GEMM for x_dbl: A[4096,2048] fp32 * W[2048,96] -> partials.
// ---------------------------------------------------------------------------
__global__ __launch_bounds__(256) void gemm_xdbl_split(
    const float* __restrict__ A,     // [BL, DINNER]
    const float* __restrict__ W,     // [DINNER, 96]
    float* __restrict__ xzbuf)       // partials region
{
    __shared__ float As[16][65];
    __shared__ float Bs[16][97];

    const int tid  = threadIdx.x;
    const int row0 = blockIdx.x * 64;
    const int kz   = blockIdx.y;
    const int kbeg = kz * KC;

    const int tr = tid >> 4;
    const int tc = tid & 15;

    const int arow = tid >> 2;
    const int akq  = (tid & 3) * 4;
    const int brow = tid >> 4;
    const int bcol = (tid & 15) * 6;

    float acc[4][6] = {};

    for (int k0 = kbeg; k0 < kbeg + KC; k0 += 16) {
        {
            float4 v = *(const float4*)(A + (size_t)(row0 + arow) * DINNER + k0 + akq);
            As[akq + 0][arow] = v.x;
            As[akq + 1][arow] = v.y;
            As[akq + 2][arow] = v.z;
            As[akq + 3][arow] = v.w;
        }
#pragma unroll
        for (int j = 0; j < 6; ++j)
            Bs[brow][bcol + j] = W[(size_t)(k0 + brow) * XDBL_N + bcol + j];
        __syncthreads();

#pragma unroll
        for (int kk = 0; kk < 16; ++kk) {
            float a[4], b[6];
#pragma unroll
            for (int i = 0; i < 4; ++i) a[i] = As[kk][tr * 4 + i];
#pragma unroll
            for (int j = 0; j < 6; ++j) b[j] = Bs[kk][tc * 6 + j];
#pragma unroll
            for (int i = 0; i < 4; ++i)
#pragma unroll
                for (int j = 0; j < 6; ++j)
                    acc[i][j] += a[i] * b[j];
        }
        __syncthreads();
    }

    const long base = (long)kz * BL * XDBL_N;
#pragma unroll
    for (int i = 0; i < 4; ++i) {
        long rowoff = base + (long)(row0 + tr * 4 + i) * XDBL_N + tc * 6;
#pragma unroll
        for (int j = 0; j < 6; ++j)
            xzbuf[part_off(rowoff + j)] = acc[i][j];
    }
}

// Reduce KSPLIT partials -> xdbl [BL, 96]; cols<64 additionally stored as
// bf16 dt_low [BL, 64] (A operand of the dt MFMA GEMM).
__global__ __launch_bounds__(256) void xdbl_reduce(
    const float* __restrict__ xzbuf, float* __restrict__ xdbl,
    __bf16* __restrict__ dtlow16)
{
    long i = (long)blockIdx.x * 256 + threadIdx.x;   // < BL*96
    float s = 0.f;
#pragma unroll
    for (int kz = 0; kz < KSPLIT; ++kz)
        s += xzbuf[part_off((long)kz * BL * XDBL_N + i)];
    xdbl[i] = s;
    int col = (int)(i % XDBL_N);
    if (col < DTRANK) {
        long row = i / XDBL_N;
        dtlow16[row * DTRANK + col] = (__bf16)s;
    }
}

// ---------------------------------------------------------------------------
// Causal depthwise conv (d_conv=4) + SiLU.
// ---------------------------------------------------------------------------
__global__ __launch_bounds__(256) void conv_silu_kernel(
    const float* __restrict__ xz,
    const float* __restrict__ cw,
    const float* __restrict__ cb,
    float* __restrict__ xc)
{
    long i = (long)blockIdx.x * blockDim.x + threadIdx.x;
    if (i >= (long)BL * DINNER) return;
    long r = i / DINNER;
    int d = (int)(i % DINNER);
    int t = (int)(r % SEQLEN);

    float acc = cb[d];
#pragma unroll
    for (int k = 0; k < DCONV; ++k) {
        int tt = t - (DCONV - 1) + k;
        if (tt >= 0)
            acc += xz[(r - (DCONV - 1) + k) * NXZ + d] * cw[d * DCONV + k];
    }
    xc[i] = silu_f(acc);
}

// ---------------------------------------------------------------------------
// Chunked parallel scan. Summaries in dead xb half of xz:
//   hloc(b,c,n) at row (b*NCHUNK+c)*16+n;  P/hstart at row 1024 + same.
// ---------------------------------------------------------------------------
__global__ __launch_bounds__(256) void scan_pass1(
    const float* __restrict__ dt,
    const float* __restrict__ xc,
    const float* __restrict__ xdbl,
    const float* __restrict__ A_log,
    float* __restrict__ sums)
{
    const int d  = blockIdx.x * 256 + threadIdx.x;
    const int bc = blockIdx.y;
    const int b  = bc / NCHUNK, c = bc % NCHUNK;
    const long r0 = (long)b * SEQLEN + (long)c * LCH;

    float Ad[DSTATE];
    {
        const float4* al = (const float4*)(A_log + d * DSTATE);
#pragma unroll
        for (int q = 0; q < 4; ++q) {
            float4 v = al[q];
            Ad[q * 4 + 0] = -__expf(v.x); Ad[q * 4 + 1] = -__expf(v.y);
            Ad[q * 4 + 2] = -__expf(v.z); Ad[q * 4 + 3] = -__expf(v.w);
        }
    }

    float h[DSTATE] = {};
    float Pp[DSTATE];
#pragma unroll
    for (int n = 0; n < DSTATE; ++n) Pp[n] = 1.f;

    for (int t = 0; t < LCH; ++t) {
        long r = r0 + t;
        float dtv = dt[r * DINNER + d];
        float xv  = xc[r * DINNER + d];
        float xdt = xv * dtv;
        const float4* bv = (const float4*)(xdbl + r * XDBL_N + DTRANK);
        float4 B0 = bv[0], B1 = bv[1], B2 = bv[2], B3 = bv[3];
        const float Bn[DSTATE] = {B0.x,B0.y,B0.z,B0.w, B1.x,B1.y,B1.z,B1.w,
                                  B2.x,B2.y,B2.z,B2.w, B3.x,B3.y,B3.z,B3.w};
#pragma unroll
        for (int n = 0; n < DSTATE; ++n) {
            float dA = __expf(Ad[n] * dtv);
            h[n] = h[n] * dA + xdt * Bn[n];
            Pp[n] *= dA;
        }
    }

    const long rowbase = (long)bc * DSTATE;
#pragma unroll
    for (int n = 0; n < DSTATE; ++n) {
        sums[(rowbase + n) * NXZ + d] = h[n];
        sums[(1024 + rowbase + n) * NXZ + d] = Pp[n];
    }
}

__global__ __launch_bounds__(256) void scan_combine(float* __restrict__ sums)
{
    int u = blockIdx.x * 256 + threadIdx.x;
    int d = u & (DINNER - 1);
    int n = (u >> 11) & (DSTATE - 1);
    int b = u >> 15;
    float hg = 0.f;
    for (int c = 0; c < NCHUNK; ++c) {
        long row = (long)(b * NCHUNK + c) * DSTATE + n;
        float p  = sums[(1024 + row) * NXZ + d];
        float hl = sums[row * NXZ + d];
        sums[(1024 + row) * NXZ + d] = hg;
        hg = p * hg + hl;
    }
}

// Pass 3: replay from hstart, fused gate, emit bf16 gated activation.
__global__ __launch_bounds__(256) void scan_pass3(
    const float* __restrict__ dt,
    const float* __restrict__ xc,
    const float* __restrict__ xdbl,
    const float* __restrict__ A_log,
    const float* __restrict__ xz,     // z half + hstart rows
    const float* __restrict__ Dp,
    __bf16* __restrict__ gated)       // [BL, DINNER] bf16
{
    const int d  = blockIdx.x * 256 + threadIdx.x;
    const int bc = blockIdx.y;
    const int b  = bc / NCHUNK, c = bc % NCHUNK;
    const long r0 = (long)b * SEQLEN + (long)c * LCH;

    float Ad[DSTATE];
    {
        const float4* al = (const float4*)(A_log + d * DSTATE);
#pragma unroll
        for (int q = 0; q < 4; ++q) {
            float4 v = al[q];
            Ad[q * 4 + 0] = -__expf(v.x); Ad[q * 4 + 1] = -__expf(v.y);
            Ad[q * 4 + 2] = -__expf(v.z); Ad[q * 4 + 3] = -__expf(v.w);
        }
    }

    float h[DSTATE];
    const long rowbase = (long)bc * DSTATE;
#pragma unroll
    for (int n = 0; n < DSTATE; ++n)
        h[n] = xz[(1024 + rowbase + n) * NXZ + d];

    const float Dv = Dp[d];

    for (int t = 0; t < LCH; ++t) {
        long r = r0 + t;
        float dtv = dt[r * DINNER + d];
        float xv  = xc[r * DINNER + d];
        float xdt = xv * dtv;
        const float4* bv = (const float4*)(xdbl + r * XDBL_N + DTRANK);
        float4 B0 = bv[0], B1 = bv[1], B2 = bv[2], B3 = bv[3];
        float4 C0 = bv[4], C1 = bv[5], C2 = bv[6], C3 = bv[7];
        const float Bn[DSTATE] = {B0.x,B0.y,B0.z,B0.w, B1.x,B1.y,B1.z,B1.w,
                                  B2.x,B2.y,B2.z,B2.w, B3.x,B3.y,B3.z,B3.w};
        const float Cn[DSTATE] = {C0.x,C0.y,C0.z,C0.w, C1.x,C1.y,C1.z,C1.w,
                                  C2.x,C2.y,C2.z,C2.w, C3.x,C3.y,C3.z,C3.w};
        float y = 0.f;
#pragma unroll
        for (int n = 0; n < DSTATE; ++n) {
            float dA = __expf(Ad[n] * dtv);
            h[n] = h[n] * dA + xdt * Bn[n];
            y += h[n] * Cn[n];
        }
        float z = xz[r * NXZ + DINNER + d];
        float yy = y + xv * Dv;
        gated[r * DINNER + d] = (__bf16)(yy * silu_f(z));
    }
}

// ---------------------------------------------------------------------------
extern "C" void kernel_launch(void* const* d_in, const int* in_sizes, int n_in,
                              void* d_out, int out_size, void* d_ws, size_t ws_size,
                              hipStream_t stream) {
    const float* x      = (const float*)d_in[0];  // [B,L,DMODEL]
    const float* W_in   = (const float*)d_in[1];  // [DMODEL, NXZ]
    const float* conv_w = (const float*)d_in[2];  // [DINNER, 4]
    const float* conv_b = (const float*)d_in[3];  // [DINNER]
    const float* W_x    = (const float*)d_in[4];  // [DINNER, 96]
    const float* W_dt   = (const float*)d_in[5];  // [DTRANK, DINNER]
    const float* b_dt   = (const float*)d_in[6];  // [DINNER]
    const float* A_log  = (const float*)d_in[7];  // [DINNER, 16]
    const float* Dp     = (const float*)d_in[8];  // [DINNER]
    const float* W_out  = (const float*)d_in[9];  // [DINNER, DMODEL]
    float* out = (float*)d_out;                   // [B,L,DMODEL]

    float* ws = (float*)d_ws;
    float* xz   = ws;                                   // 16.78M floats
    float* xc   = xz + (long)BL * NXZ;                  //  8.39M
    float* xdbl = xc + (long)BL * DINNER;               //  0.39M
    float* dt   = xdbl + (long)BL * XDBL_N;             //  8.39M
    __bf16* gated16 = (__bf16*)(dt + (long)BL * DINNER);              // BL*DINNER bf16
    __bf16* WoT16   = (__bf16*)((float*)gated16 + (long)BL * DINNER / 2); // DINNER*DMODEL bf16
    __bf16* WdtT16  = WoT16 + (long)DINNER * DMODEL;    // [DINNER, 64] bf16
    __bf16* dtlow16 = WdtT16 + (long)DINNER * DTRANK;   // [BL, 64] bf16
    // xb16 / W_inT16 alias the xc region (dead until conv)
    __bf16* xb16  = (__bf16*)xc;
    __bf16* WiT16 = (__bf16*)(xc + (long)BL * DMODEL / 2);
    // total ws ~158 MB

    dim3 blk(256);

    // 0) casts: x -> bf16; W_in -> bf16^T; W_out -> bf16^T; W_dt -> bf16^T
    cast_bf16_kernel<<<dim3((BL * DMODEL / 4) / 256), blk, 0, stream>>>(
        x, xb16, (long)BL * DMODEL);
    transpose_cast<<<dim3(NXZ / 32, DMODEL / 32), dim3(32, 8), 0, stream>>>(
        W_in, WiT16, DMODEL, NXZ);
    transpose_cast<<<dim3(DMODEL / 32, DINNER / 32), dim3(32, 8), 0, stream>>>(
        W_out, WoT16, DINNER, DMODEL);
    transpose_cast<<<dim3(DINNER / 32, DTRANK / 32), dim3(32, 8), 0, stream>>>(
        W_dt, WdtT16, DTRANK, DINNER);

    // 1) xz = x @ W_in   (MFMA bf16)
    gemm_bt_mfma<0><<<dim3(NXZ / 128, BL / 128), blk, 0, stream>>>(
        xb16, WiT16, xz, BL, NXZ, DMODEL, nullptr);

    // 2) causal depthwise conv + silu -> xc (overwrites xb16/WiT16 — dead now)
    {
        long total = (long)BL * DINNER;
        conv_silu_kernel<<<dim3((unsigned)((total + 255) / 256)), blk, 0, stream>>>(
            xz, conv_w, conv_b, xc);
    }
    // 3) x_dbl = xc @ W_x   (split-K into dead xb half of xz, then reduce;
    //    reduce also emits dt_low as bf16)
    gemm_xdbl_split<<<dim3(BL / 64, KSPLIT), blk, 0, stream>>>(xc, W_x, xz);
    xdbl_reduce<<<dim3((BL * XDBL_N) / 256), blk, 0, stream>>>(xz, xdbl, dtlow16);

    // 4) dt = softplus(dt_low @ W_dt + b_dt)   (MFMA bf16, K=64, fast softplus)
    gemm_bt_mfma<1><<<dim3(DINNER / 128, BL / 128), blk, 0, stream>>>(
        dtlow16, WdtT16, dt, BL, DINNER, DTRANK, b_dt);

    // 5) chunked scan: pass1 -> combine -> pass3 (+fused gate, bf16 out)
    {
        dim3 grid1(DINNER / 256, BATCH * NCHUNK);
        scan_pass1<<<grid1, blk, 0, stream>>>(dt, xc, xdbl, A_log, xz);
        scan_combine<<<dim3((BATCH * DSTATE * DINNER) / 256), blk, 0, stream>>>(xz);
        scan_pass3<<<grid1, blk, 0, stream>>>(dt, xc, xdbl, A_log, xz, Dp, gated16);
    }
    // 7) out = gated @ W_out   (MFMA bf16)
    gemm_bt_mfma<0><<<dim3(DMODEL / 128, BL / 128), blk, 0, stream>>>(
        gated16, WoT16, out, BL, DMODEL, DINNER, nullptr);

    (void)in_sizes; (void)n_in; (void)out_size; (void)ws_size;
}